// Round 8
// baseline (207.563 us; speedup 1.0000x reference)
//
#include <hip/hip_runtime.h>
#include <hip/hip_bf16.h>
#include <math.h>

// Problem dims (fixed by setup_inputs)
#define B_  8
#define CM  80
#define T1_ 800
#define CT  512
#define T2_ 200
#define CA  80

using bf16 = __hip_bfloat16;
typedef __attribute__((ext_vector_type(8))) short bf16x8;
typedef __attribute__((ext_vector_type(4))) float f32x4;

#define LDSW 56
#define LDSW2 72    // key-conv B row stride (BK=64 + pad)
#define LDSW3 168   // fused conv23 stage-1 row stride (K=160)
#define LDSW4 104   // fused conv23 stage-2 row stride (K=96 padded)

#define NBLK 512    // fused conv kernel grid; (256,2) guarantees residency

__device__ __forceinline__ float load_sel(const void* p, long idx, int isf32) {
  if (isf32) return ((const float*)p)[idx];
  return __bfloat162float(((const bf16*)p)[idx]);
}

__device__ __forceinline__ unsigned short f2bf(float x) {
  bf16 h = __float2bfloat16(x);
  return *reinterpret_cast<unsigned short*>(&h);
}

// Inline dtype probe (R8-R11 proven).
__device__ __forceinline__ int detect_f32(const unsigned short* q) {
  __shared__ int s_f;
  const int tid = threadIdx.x;
  if (tid < 64) {
    unsigned short u = q[2 * tid];
    int e = (u >> 7) & 0xFF;
    unsigned long long bal = __ballot(e < 100 || e > 154);
    if (tid == 0) s_f = (__popcll(bal) >= 16) ? 1 : 0;
  }
  __syncthreads();
  return s_f;
}

// Device-scope grid barrier (R2-validated machinery). All NBLK blocks are
// co-resident: launch_bounds(256,2) + LDS 48.4KB (3 blocks/CU by LDS).
__device__ __forceinline__ void grid_bar(int* cnt) {
  __syncthreads();
  if (threadIdx.x == 0) {
    __threadfence();                       // release
    int arrived = atomicAdd(cnt, 1) + 1;
    if (arrived < NBLK) {
      while (atomicAdd(cnt, 0) < NBLK) __builtin_amdgcn_s_sleep(4);
    }
    __threadfence();                       // acquire
  }
  __syncthreads();
}

// ---------------------------------------------------------------------------
// Prep tasks (R4-proven).
// ---------------------------------------------------------------------------
__device__ void task_cvt_t(const void* X, bf16* XT, int f, int C, int T,
                           int id2, int tilesT, float* smem, int tid) {
  const int per_b = tilesT * ((C + 31) >> 5);
  const int b = id2 / per_b;
  const int r = id2 - b * per_b;
  const int ct = r / tilesT, tt = r - ct * tilesT;
  const int c0 = ct * 32, t0 = tt * 32;
  const int tx = tid & 31, trow = tid >> 5;
#pragma unroll
  for (int p = 0; p < 4; ++p) {
    const int cr = trow + 8 * p;
    if (c0 + cr < C && t0 + tx < T)
      smem[cr * 33 + tx] = load_sel(X, ((long)b * C + c0 + cr) * T + t0 + tx, f);
  }
  __syncthreads();
#pragma unroll
  for (int p = 0; p < 4; ++p) {
    const int tr = trow + 8 * p;
    if (t0 + tr < T && c0 + tx < C)
      XT[((long)b * T + t0 + tr) * C + c0 + tx] =
          __float2bfloat16(smem[tx * 33 + tr]);
  }
}

// kp_w1 -> MFMA-fragment-ordered w1F: [panel8][ks24][w2:2][mi:4][h:2][lane64][e8]
__device__ void task_wfrag(const void* W, bf16* WF, int f, int id2, int tid) {
  const int id = id2 * 256 + tid;            // 0 .. 196607
  const int l  = id & 63;
  int rest = id >> 6;                        // 0..3071
  const int h  = rest & 1; rest >>= 1;
  const int mi = rest & 3; rest >>= 2;
  const int w2 = rest & 1; rest >>= 1;
  const int ks = rest % 24;
  const int p  = rest / 24;
  const int co = p * 128 + w2 * 64 + mi * 16 + (l & 15);
  const int k0 = ks * 64 + h * 32 + (l >> 4) * 8;
  const int dk = k0 >> 9;
  const int ci = k0 & 511;
  const long sbase = ((long)co * 512 + ci) * 3 + dk;
  ushort4 u0, u1;
  u0.x = f2bf(load_sel(W, sbase + 0 * 3, f));
  u0.y = f2bf(load_sel(W, sbase + 1 * 3, f));
  u0.z = f2bf(load_sel(W, sbase + 2 * 3, f));
  u0.w = f2bf(load_sel(W, sbase + 3 * 3, f));
  u1.x = f2bf(load_sel(W, sbase + 4 * 3, f));
  u1.y = f2bf(load_sel(W, sbase + 5 * 3, f));
  u1.z = f2bf(load_sel(W, sbase + 6 * 3, f));
  u1.w = f2bf(load_sel(W, sbase + 7 * 3, f));
  *(ushort4*)(WF + (long)id * 8) = u0;
  *(ushort4*)(WF + (long)id * 8 + 4) = u1;
}

__device__ void task_wt3v(const void* W, bf16* WT, int f, int Co, int Ci,
                          int id2, int tid) {
  const int i = id2 * 256 + tid;
  const int g4 = Ci >> 2;
  if (i >= Co * g4) return;
  const int co = i / g4, ci = (i - co * g4) * 4;
  const long sbase = ((long)co * Ci + ci) * 3;
  float w[12];
  if (f) {
    const float4* s = (const float4*)((const float*)W + sbase);
    float4 f0 = s[0], f1 = s[1], f2 = s[2];
    w[0]=f0.x; w[1]=f0.y; w[2]=f0.z; w[3]=f0.w; w[4]=f1.x; w[5]=f1.y;
    w[6]=f1.z; w[7]=f1.w; w[8]=f2.x; w[9]=f2.y; w[10]=f2.z; w[11]=f2.w;
  } else {
#pragma unroll
    for (int j = 0; j < 12; ++j) w[j] = load_sel(W, sbase + j, 0);
  }
#pragma unroll
  for (int dk = 0; dk < 3; ++dk) {
    ushort4 u;
    u.x = f2bf(w[0 * 3 + dk]); u.y = f2bf(w[1 * 3 + dk]);
    u.z = f2bf(w[2 * 3 + dk]); u.w = f2bf(w[3 * 3 + dk]);
    *(ushort4*)(WT + ((long)dk * Co + co) * Ci + ci) = u;
  }
}

__device__ void task_cvtv(const void* W, bf16* O, int f, int n, int id2, int tid) {
  const int i = (id2 * 256 + tid) * 4;
  if (i >= n) return;
  ushort4 u;
  if (f) {
    float4 v = *(const float4*)((const float*)W + i);
    u.x = f2bf(v.x); u.y = f2bf(v.y); u.z = f2bf(v.z); u.w = f2bf(v.w);
  } else {
    u.x = f2bf(load_sel(W, i, 0));     u.y = f2bf(load_sel(W, i + 1, 0));
    u.z = f2bf(load_sel(W, i + 2, 0)); u.w = f2bf(load_sel(W, i + 3, 0));
  }
  *(ushort4*)(O + i) = u;
}

__global__ __launch_bounds__(256) void k_prep(
    const void* __restrict__ queries, const void* __restrict__ keys,
    const void* __restrict__ mask,
    const void* __restrict__ kp_w1, const void* __restrict__ kp_b1,
    const void* __restrict__ kp_w2, const void* __restrict__ kp_b2,
    const void* __restrict__ qp_w1, const void* __restrict__ qp_b1,
    const void* __restrict__ qp_w2, const void* __restrict__ qp_b2,
    const void* __restrict__ qp_w3, const void* __restrict__ qp_b3,
    bf16* __restrict__ keysT, bf16* __restrict__ queriesT,
    bf16* __restrict__ w1F, bf16* __restrict__ qw1T,
    bf16* __restrict__ kw2c, bf16* __restrict__ qw2c, bf16* __restrict__ qw3c,
    float* __restrict__ biasf, float* __restrict__ mf, float* __restrict__ kn) {
  __shared__ float smem[32 * 33];
  const int tid = threadIdx.x;
  const int f = detect_f32((const unsigned short*)queries);
  int id = blockIdx.x;

  if (id < 896) { task_cvt_t(keys, keysT, f, CT, T2_, id, 7, smem, tid); return; }
  id -= 896;
  if (id < 600) { task_cvt_t(queries, queriesT, f, CM, T1_, id, 25, smem, tid); return; }
  id -= 600;
  if (id < 768) { task_wfrag(kp_w1, w1F, f, id, tid); return; }
  id -= 768;
  if (id < 13) { task_wt3v(qp_w1, qw1T, f, 160, CM, id, tid); return; }
  id -= 13;
  if (id < 80) { task_cvtv(kp_w2, kw2c, f, 80 * 1024, id, tid); return; }
  id -= 80;
  if (id < 13) { task_cvtv(qp_w2, qw2c, f, 80 * 160, id, tid); return; }
  id -= 13;
  if (id < 7) { task_cvtv(qp_w3, qw3c, f, 80 * 80, id, tid); return; }
  id -= 7;

  if (id == 0) {
    for (int i = tid; i < 1424; i += 256) {
      float v;
      if (i < 1024)      v = load_sel(kp_b1, i, f);
      else if (i < 1104) v = load_sel(kp_b2, i - 1024, f);
      else if (i < 1264) v = load_sel(qp_b1, i - 1104, f);
      else if (i < 1344) v = load_sel(qp_b2, i - 1264, f);
      else               v = load_sel(qp_b3, i - 1344, f);
      biasf[i] = v;
    }
    // zero key-norm accumulator (conv2 atomically accumulates into it)
    for (int i = tid; i < B_ * T2_; i += 256) kn[i] = 0.f;
    return;
  }

  // mask normalize (R2-proven format detection)
  {
    int* s_fmt = (int*)smem;
    const int nmask = B_ * T2_;
    if (tid == 0) s_fmt[0] = 1;
    __syncthreads();
    const unsigned int* wi = (const unsigned int*)mask;
    const int nw = nmask / 4;
    int pri = 0;
    for (int i = tid; i < nw; i += 256) {
      unsigned int w = wi[i];
      if (w == 0u || w == 1u) continue;
      if (w == 0x3F803F80u || w == 0x00003F80u) { pri = max(pri, 2); continue; }
      if (w == 0x3F800000u) continue;
      unsigned int b0 = w & 0xFFu, b1 = (w >> 8) & 0xFFu,
                   b2 = (w >> 16) & 0xFFu, b3 = (w >> 24) & 0xFFu;
      if (b0 <= 1u && b1 <= 1u && b2 <= 1u && b3 <= 1u) pri = max(pri, 3);
      else pri = max(pri, 2);
    }
    if (pri) atomicMax(&s_fmt[0], pri);
    __syncthreads();
    const int fmt = s_fmt[0];
    for (int i = tid; i < nmask; i += 256) {
      int m;
      if (fmt == 3)      m = ((const unsigned char*)mask)[i] != 0;
      else if (fmt == 2) m = ((const unsigned short*)mask)[i] != 0;
      else               m = (wi[i] != 0u);
      mf[i] = (float)m;
    }
  }
}

// ---------------------------------------------------------------------------
// Generic conv tile, BK=32 (R4-proven) + reg-prefetch.
// outmode: 0 = bf16 [n][Cout]; 1 = fp32 [n][Cout];
// 2 = keT [b][80][200] = -2v + atomicAdd v^2 into Y2.
// ---------------------------------------------------------------------------
__device__ void conv_tile(
    const bf16* __restrict__ XT, const bf16* __restrict__ WT,
    const float* __restrict__ bias, void* __restrict__ Y,
    int Cin, int Cout, int T, int KW, int pad, int relu, int outmode,
    int m0, int n0, short* As, short* Bs, float* Y2 = nullptr) {
  const int K = Cin * KW;
  const int tid = threadIdx.x;
  const int wave = tid >> 6;
  const int lane = tid & 63;

  const int row = tid >> 2;
  const int koff = (tid & 3) * 8;
  const int n = n0 + row;
  const int bb = n / T;
  const int t = n - bb * T;

  const int wm = (wave >> 1) * 32;
  const int wn = (wave & 1) * 32;
  const int fm = lane & 15;
  const int quad = lane >> 4;

  f32x4 acc[2][2] = {};

  const short* ap0 = As + (wm + fm) * LDSW + quad * 8;
  const short* bp0 = Bs + (wn + fm) * LDSW + quad * 8;

  auto loadA = [&](int k0) -> uint4 {
    const int k = k0 + koff;
    const int m = m0 + row;
    uint4 v = {0u, 0u, 0u, 0u};
    if (m < Cout && k < K) {
      const int dk = k / Cin;
      const int ci = k - dk * Cin;
      v = *(const uint4*)(WT + ((long)dk * Cout + m) * Cin + ci);
    }
    return v;
  };
  auto loadB = [&](int k0) -> uint4 {
    const int k = k0 + koff;
    uint4 v = {0u, 0u, 0u, 0u};
    if (k < K) {
      const int dk = k / Cin;
      const int ci = k - dk * Cin;
      const int tt = t + dk - pad;
      if (tt >= 0 && tt < T)
        v = *(const uint4*)(XT + ((long)bb * T + tt) * Cin + ci);
    }
    return v;
  };

  uint4 va = loadA(0);
  uint4 vb = loadB(0);

  for (int k0 = 0; k0 < K; k0 += 32) {
    *(uint4*)(As + row * LDSW + koff) = va;
    *(uint4*)(Bs + row * LDSW + koff) = vb;
    if (k0 + 32 < K) {
      va = loadA(k0 + 32);
      vb = loadB(k0 + 32);
    }
    __syncthreads();
    {
      bf16x8 a0 = *(const bf16x8*)(ap0);
      bf16x8 a1 = *(const bf16x8*)(ap0 + 16 * LDSW);
      bf16x8 b0 = *(const bf16x8*)(bp0);
      bf16x8 b1 = *(const bf16x8*)(bp0 + 16 * LDSW);
      acc[0][0] = __builtin_amdgcn_mfma_f32_16x16x32_bf16(a0, b0, acc[0][0], 0, 0, 0);
      acc[0][1] = __builtin_amdgcn_mfma_f32_16x16x32_bf16(a0, b1, acc[0][1], 0, 0, 0);
      acc[1][0] = __builtin_amdgcn_mfma_f32_16x16x32_bf16(a1, b0, acc[1][0], 0, 0, 0);
      acc[1][1] = __builtin_amdgcn_mfma_f32_16x16x32_bf16(a1, b1, acc[1][1], 0, 0, 0);
    }
    __syncthreads();
  }

#pragma unroll
  for (int mi = 0; mi < 2; ++mi) {
    const int mrow = m0 + wm + mi * 16 + quad * 4;
    if (mrow >= Cout) continue;
    float bi[4];
#pragma unroll
    for (int r = 0; r < 4; ++r) bi[r] = bias[mrow + r];
#pragma unroll
    for (int ni = 0; ni < 2; ++ni) {
      const int ncol = n0 + wn + ni * 16 + fm;
      float o[4];
#pragma unroll
      for (int r = 0; r < 4; ++r) {
        float v = acc[mi][ni][r] + bi[r];
        if (relu) v = fmaxf(v, 0.f);
        o[r] = v;
      }
      if (outmode == 0) {
        ushort4 u;
        u.x = f2bf(o[0]); u.y = f2bf(o[1]); u.z = f2bf(o[2]); u.w = f2bf(o[3]);
        *(ushort4*)((bf16*)Y + (long)ncol * Cout + mrow) = u;
      } else if (outmode == 1) {
        *(float4*)((float*)Y + (long)ncol * Cout + mrow) =
            make_float4(o[0], o[1], o[2], o[3]);
      } else {
        // keT [b][Cout][T] = -2v, channel-major for coalesced dist reads
        const int bb2 = ncol / T;
        const int tloc = ncol - bb2 * T;
        float s4 = 0.f;
#pragma unroll
        for (int r = 0; r < 4; ++r) {
          ((float*)Y)[((long)bb2 * Cout + mrow + r) * T + tloc] = -2.f * o[r];
          s4 = fmaf(o[r], o[r], s4);
        }
        atomicAdd(&Y2[ncol], s4);
      }
    }
  }
}

// ---------------------------------------------------------------------------
// Key-conv1, 128x64 tile, BK=64 (R7-proven): A direct from w1F with
// ping-pong prefetch, B reg-prefetch -> LDS per step.
// ---------------------------------------------------------------------------
__device__ void conv_key128(
    const bf16* __restrict__ XT, const bf16* __restrict__ WF,
    const float* __restrict__ bias, bf16* __restrict__ Y,
    int panel, int n0, short* Bs) {
  const int Cin = CT, Cout = 1024, T = T2_;
  const int tid = threadIdx.x;
  const int wave = tid >> 6;
  const int lane = tid & 63;
  const int m0 = panel * 128;

  const int rowb = tid >> 2;
  const int nb = n0 + rowb;
  const int bbb = nb / T;
  const int tb = nb - bbb * T;
  const int kcb = (tid & 3) * 16;

  const int w2 = wave >> 1;
  const int wn = (wave & 1) * 32;
  const int fm = lane & 15;
  const int quad = lane >> 4;

  f32x4 acc[4][2] = {};
  const short* bp0 = Bs + (wn + fm) * LDSW2 + quad * 8;

  uint4 vb0, vb1;
  auto loadB = [&](int k0) {
    const int dk = k0 >> 9;
    const int ci0 = k0 & 511;
    const int tt = tb + dk - 1;
    if (tt >= 0 && tt < T) {
      const bf16* src = XT + ((long)bbb * T + tt) * Cin + ci0 + kcb;
      vb0 = *(const uint4*)(src);
      vb1 = *(const uint4*)(src + 8);
    } else {
      uint4 z = {0u, 0u, 0u, 0u};
      vb0 = z; vb1 = z;
    }
  };

  bf16x8 a0c[4], a1c[4], a0n[4], a1n[4];
  auto loadA = [&](int ks, bf16x8 d0[4], bf16x8 d1[4]) {
    const long abase = ((((long)panel * 24 + ks) * 2 + w2) * 4096) + lane * 8;
#pragma unroll
    for (int mi = 0; mi < 4; ++mi) {
      d0[mi] = *(const bf16x8*)(WF + abase + (mi * 2 + 0) * 512);
      d1[mi] = *(const bf16x8*)(WF + abase + (mi * 2 + 1) * 512);
    }
  };

  loadB(0);
  loadA(0, a0c, a1c);

  for (int k0 = 0; k0 < 1536; k0 += 64) {
    {
      short* dstb = Bs + rowb * LDSW2 + kcb;
      *(uint4*)(dstb) = vb0;
      *(uint4*)(dstb + 8) = vb1;
    }
    const bool more = (k0 + 64 < 1536);
    if (more) {
      loadB(k0 + 64);
      loadA((k0 >> 6) + 1, a0n, a1n);
    }
    __syncthreads();
    {
      bf16x8 b00 = *(const bf16x8*)(bp0);
      bf16x8 b01 = *(const bf16x8*)(bp0 + 16 * LDSW2);
#pragma unroll
      for (int mi = 0; mi < 4; ++mi) {
        acc[mi][0] = __builtin_amdgcn_mfma_f32_16x16x32_bf16(a0c[mi], b00, acc[mi][0], 0, 0, 0);
        acc[mi][1] = __builtin_amdgcn_mfma_f32_16x16x32_bf16(a0c[mi], b01, acc[mi][1], 0, 0, 0);
      }
      bf16x8 b10 = *(const bf16x8*)(bp0 + 32);
      bf16x8 b11 = *(const bf16x8*)(bp0 + 16 * LDSW2 + 32);
#pragma unroll
      for (int mi = 0; mi < 4; ++mi) {
        acc[mi][0] = __builtin_amdgcn_mfma_f32_16x16x32_bf16(a1c[mi], b10, acc[mi][0], 0, 0, 0);
        acc[mi][1] = __builtin_amdgcn_mfma_f32_16x16x32_bf16(a1c[mi], b11, acc[mi][1], 0, 0, 0);
      }
    }
    __syncthreads();
    if (more) {
#pragma unroll
      for (int mi = 0; mi < 4; ++mi) { a0c[mi] = a0n[mi]; a1c[mi] = a1n[mi]; }
    }
  }

#pragma unroll
  for (int mi = 0; mi < 4; ++mi) {
    const int mrow = m0 + w2 * 64 + mi * 16 + quad * 4;
    float bi[4];
#pragma unroll
    for (int r = 0; r < 4; ++r) bi[r] = bias[mrow + r];
#pragma unroll
    for (int ni = 0; ni < 2; ++ni) {
      const int ncol = n0 + wn + ni * 16 + fm;
      const long base = (long)ncol * Cout + mrow;
      ushort4 u;
      u.x = f2bf(fmaxf(acc[mi][ni][0] + bi[0], 0.f));
      u.y = f2bf(fmaxf(acc[mi][ni][1] + bi[1], 0.f));
      u.z = f2bf(fmaxf(acc[mi][ni][2] + bi[2], 0.f));
      u.w = f2bf(fmaxf(acc[mi][ni][3] + bi[3], 0.f));
      *(ushort4*)(Y + base) = u;
    }
  }
}

// ---------------------------------------------------------------------------
// Fused query conv2+conv3 (R4-proven) + qn (||q||^2) epilogue.
// ---------------------------------------------------------------------------
__device__ void conv23_tile(
    const bf16* __restrict__ qe1T, const bf16* __restrict__ qw2c,
    const float* __restrict__ b_q2, const bf16* __restrict__ qw3c,
    const float* __restrict__ b_q3, float* __restrict__ qeT,
    float* __restrict__ qn, int n0, short* smem) {
  short* sIn = smem;
  short* sW2 = smem + 64 * LDSW3;
  short* sC  = smem;
  short* sW3 = smem + 64 * LDSW3;
  const int tid = threadIdx.x;
  const int wave = tid >> 6;
  const int lane = tid & 63;
  const int fm = lane & 15;
  const int quad = lane >> 4;

#pragma unroll
  for (int c = tid; c < 1280; c += 256) {
    const int row = c / 20, kc = (c - row * 20) * 8;
    uint4 v = *(const uint4*)(qe1T + (long)(n0 + row) * 160 + kc);
    *(uint4*)(sIn + row * LDSW3 + kc) = v;
  }
  for (int c = tid; c < 1600; c += 256) {
    const int row = c / 20, kc = (c - row * 20) * 8;
    uint4 v = *(const uint4*)(qw2c + (long)row * 160 + kc);
    *(uint4*)(sW2 + row * LDSW3 + kc) = v;
  }
  __syncthreads();

  f32x4 acc1[5] = {};
#pragma unroll
  for (int ks = 0; ks < 5; ++ks) {
    bf16x8 b = *(const bf16x8*)(sIn + (16 * wave + fm) * LDSW3 + ks * 32 + quad * 8);
#pragma unroll
    for (int mt = 0; mt < 5; ++mt) {
      bf16x8 a = *(const bf16x8*)(sW2 + (16 * mt + fm) * LDSW3 + ks * 32 + quad * 8);
      acc1[mt] = __builtin_amdgcn_mfma_f32_16x16x32_bf16(a, b, acc1[mt], 0, 0, 0);
    }
  }
  __syncthreads();

#pragma unroll
  for (int mt = 0; mt < 5; ++mt) {
    const int ch = 16 * mt + quad * 4;
    const float4 b2 = *(const float4*)(b_q2 + ch);
    ushort4 u;
    u.x = f2bf(fmaxf(acc1[mt][0] + b2.x, 0.f));
    u.y = f2bf(fmaxf(acc1[mt][1] + b2.y, 0.f));
    u.z = f2bf(fmaxf(acc1[mt][2] + b2.z, 0.f));
    u.w = f2bf(fmaxf(acc1[mt][3] + b2.w, 0.f));
    *(ushort4*)(sC + (16 * wave + fm) * LDSW4 + ch) = u;
  }
  if (tid < 128) {
    const int row = tid >> 1, off = 80 + (tid & 1) * 8;
    uint4 z = {0u, 0u, 0u, 0u};
    *(uint4*)(sC + row * LDSW4 + off) = z;
  }
  for (int c = tid; c < 800; c += 256) {
    const int row = c / 10, kc = (c - row * 10) * 8;
    uint4 v = *(const uint4*)(qw3c + (long)row * 80 + kc);
    *(uint4*)(sW3 + row * LDSW4 + kc) = v;
  }
  if (tid < 160) {
    const int row = tid >> 1, off = 80 + (tid & 1) * 8;
    uint4 z = {0u, 0u, 0u, 0u};
    *(uint4*)(sW3 + row * LDSW4 + off) = z;
  }
  __syncthreads();

  f32x4 acc2[5] = {};
#pragma unroll
  for (int ks = 0; ks < 3; ++ks) {
    bf16x8 b = *(const bf16x8*)(sC + (16 * wave + fm) * LDSW4 + ks * 32 + quad * 8);
#pragma unroll
    for (int mt = 0; mt < 5; ++mt) {
      bf16x8 a = *(const bf16x8*)(sW3 + (16 * mt + fm) * LDSW4 + ks * 32 + quad * 8);
      acc2[mt] = __builtin_amdgcn_mfma_f32_16x16x32_bf16(a, b, acc2[mt], 0, 0, 0);
    }
  }

  const int pos = n0 + 16 * wave + fm;
  float p = 0.f;
#pragma unroll
  for (int mt = 0; mt < 5; ++mt) {
    const int ch = 16 * mt + quad * 4;
    const float4 b3 = *(const float4*)(b_q3 + ch);
    float4 o = make_float4(acc2[mt][0] + b3.x, acc2[mt][1] + b3.y,
                           acc2[mt][2] + b3.z, acc2[mt][3] + b3.w);
    p = fmaf(o.x, o.x, p); p = fmaf(o.y, o.y, p);
    p = fmaf(o.z, o.z, p); p = fmaf(o.w, o.w, p);
    *(float4*)(qeT + (long)pos * CA + ch) = o;
  }
  p += __shfl_xor(p, 16, 64);
  p += __shfl_xor(p, 32, 64);
  if (quad == 0) qn[pos] = p;
}

// ---------------------------------------------------------------------------
// Fused conv kernel: phase 1 = conv1 (500 tasks), grid barrier,
// phase 2 = conv2f (150 tasks). Grid 512, (256,2): co-residency guaranteed
// (LDS 48.4KB -> 3 blocks/CU; 2 needed). Saves one launch boundary.
// ---------------------------------------------------------------------------
__global__ __launch_bounds__(256, 2) void k_convs(
    const bf16* __restrict__ keysT, const bf16* __restrict__ w1F,
    const float* __restrict__ b_k1, bf16* __restrict__ ke1T,
    const bf16* __restrict__ queriesT, const bf16* __restrict__ qw1T,
    const float* __restrict__ b_q1, bf16* __restrict__ qe1T,
    const bf16* __restrict__ kw2c, const float* __restrict__ b_k2,
    float* __restrict__ keT, float* __restrict__ kn,
    const bf16* __restrict__ qw2c, const float* __restrict__ b_q2,
    const bf16* __restrict__ qw3c, const float* __restrict__ b_q3,
    float* __restrict__ qeT, float* __restrict__ qn,
    int* __restrict__ bars) {
  __shared__ __align__(16) short smem[144 * LDSW3];   // 48.4 KB, all phases
  const int j = blockIdx.x;

  // ---- Phase 1: conv1 ----
  if (j < 200) {
    // panel = j&7 -> XCD-affine (round-robin dispatch preserves j%8->XCD).
    conv_key128(keysT, w1F, b_k1, ke1T, j & 7, (j >> 3) * 64, smem);
  } else if (j < 500) {
    const int q = j - 200;
    conv_tile(queriesT, qw1T, b_q1, qe1T, CM, 160, T1_, 3, 1, 1, 0,
              (q / 100) * 64, (q % 100) * 64, smem, smem + 64 * LDSW);
  }

  grid_bar(&bars[0]);

  // ---- Phase 2: conv2f ----
  if (j < 50) {
    conv_tile(ke1T, kw2c, b_k2, keT, 1024, CA, T2_, 1, 0, 0, 2,
              (j / 25) * 64, (j % 25) * 64, smem, smem + 64 * LDSW, kn);
  } else if (j < 150) {
    conv23_tile(qe1T, qw2c, b_q2, qw3c, b_q3, qeT, qn, (j - 50) * 64, smem);
  }
}

// ---------------------------------------------------------------------------
// dist: 4 t1-rows per block, 2-phase reduction (R7-proven).
// ---------------------------------------------------------------------------
__global__ __launch_bounds__(256) void k_dist(
    const float* __restrict__ qeT, const float* __restrict__ keT2,
    const float* __restrict__ kn, const float* __restrict__ qn,
    const void* __restrict__ prior, const float* __restrict__ mf,
    void* __restrict__ out, const unsigned short* __restrict__ qprobe) {
  __shared__ float sq[4 * CA];
  __shared__ float sqn[4];
  __shared__ float redA[16], redB[16], redC[16], redD[16];
  const int f = detect_f32(qprobe);
  const int b = blockIdx.y;
  const int t1base = blockIdx.x * 4;
  const int tid = threadIdx.x;
  const int wid = tid >> 6;

  const int t2 = tid;
  const bool valid = (t2 < T2_);
  const long N = (long)B_ * T1_ * T2_;

  float pr[4] = {0.f, 0.f, 0.f, 0.f};
  float mval = 1.f;
  if (valid) {
#pragma unroll
    for (int u = 0; u < 4; ++u)
      pr[u] = load_sel(prior, ((long)b * T1_ + t1base + u) * T2_ + t2, f);
    mval = mf[b * T2_ + t2];
  }

  for (int i = tid; i < 4 * CA; i += 256) {
    int u = i / CA, c = i - u * CA;
    sq[i] = qeT[((long)b * T1_ + t1base + u) * CA + c];
  }
  if (tid < 4) sqn[tid] = qn[b * T1_ + t1base + tid];
  __syncthreads();

  float x[4] = {-INFINITY, -INFINITY, -INFINITY, -INFINITY};
  if (valid) {
    const float* kp = keT2 + (long)b * CA * T2_ + t2;
    const float knv = kn[b * T2_ + t2];
    float a0 = 0.f, a1 = 0.f, a2 = 0.f, a3 = 0.f;
#pragma unroll 2
    for (int j = 0; j < CA; j += 4) {
      const float4 q0 = *(const float4*)(sq + 0 * CA + j);
      const float4 q1 = *(const float4*)(sq + 1 * CA + j);
      const float4 q2 = *(const float4*)(sq + 2 * CA + j);
      const float4 q3 = *(const float4*)(sq + 3 * CA + j);
      const float k0v = kp[(j + 0) * T2_];
      const float k1v = kp[(j + 1) * T2_];
      const float k2v = kp[(j + 2) * T2_];
      const float k3v = kp[(j + 3) * T2_];
      a0 = fmaf(k0v, q0.x, a0); a0 = fmaf(k1v, q0.y, a0);
      a0 = fmaf(k2v, q0.z, a0); a0 = fmaf(k3v, q0.w, a0);
      a1 = fmaf(k0v, q1.x, a1); a1 = fmaf(k1v, q1.y, a1);
      a1 = fmaf(k2v, q1.z, a1); a1 = fmaf(k3v, q1.w, a1);
      a2 = fmaf(k0v, q2.x, a2); a2 = fmaf(k1v, q2.y, a2);
      a2 = fmaf(k2v, q2.z, a2); a2 = fmaf(k3v, q2.w, a2);
      a3 = fmaf(k0v, q3.x, a3); a3 = fmaf(k1v, q3.y, a3);
      a3 = fmaf(k2v, q3.z, a3); a3 = fmaf(k3v, q3.w, a3);
    }
    x[0] = -0.0005f * (a0 + sqn[0] + knv);
    x[1] = -0.0005f * (a1 + sqn[1] + knv);
    x[2] = -0.0005f * (a2 + sqn[2] + knv);
    x[3] = -0.0005f * (a3 + sqn[3] + knv);
  }

  float y[4], ym[4];
#pragma unroll
  for (int u = 0; u < 4; ++u) {
    if (valid) {
      const float lpr = __logf(fmaxf(pr[u], 0.f) + 1e-8f);
      y[u] = x[u] + lpr;
    } else {
      y[u] = -INFINITY;
    }
    ym[u] = (valid && mval == 0.f) ? y[u] : -INFINITY;
  }

  // --- phase A: max(x) and maskedmax(y) ---
  float m1[4], m2[4];
#pragma unroll
  for (int u = 0; u < 4; ++u) { m1[u] = x[u]; m2[u] = ym[u]; }
#pragma unroll
  for (int o = 32; o > 0; o >>= 1)
#pragma unroll
    for (int u = 0; u < 4; ++u) {
      m1[u] = fmaxf(m1[u], __shfl_down(m1[u], o, 64));
      m2[u] = fmaxf(m2[u], __shfl_down(m2[u], o, 64));
    }
  if ((tid & 63) == 0)
#pragma unroll
    for (int u = 0; u < 4; ++u) {
      redA[wid * 4 + u] = m1[u];
      redB[wid * 4 + u] = m2[u];
    }
  __syncthreads();
  float M1[4], M2[4];
#pragma unroll
  for (int u = 0; u < 4; ++u) {
    M1[u] = fmaxf(fmaxf(redA[u], redA[4 + u]), fmaxf(redA[8 + u], redA[12 + u]));
    M2[u] = fmaxf(fmaxf(redB[u], redB[4 + u]), fmaxf(redB[8 + u], redB[12 + u]));
  }

  // --- phase B: both exp-sums ---
  float e2[4], s1[4], s2[4];
#pragma unroll
  for (int u = 0; u < 4; ++u) {
    s1[u] = (x[u] == -INFINITY) ? 0.f : __expf(x[u] - M1[u]);
    e2[u] = (ym[u] == -INFINITY) ? 0.f : __expf(ym[u] - M2[u]);
    s2[u] = e2[u];
  }
#pragma unroll
  for (int o = 32; o > 0; o >>= 1)
#pragma unroll
    for (int u = 0; u < 4; ++u) {
      s1[u] += __shfl_down(s1[u], o, 64);
      s2[u] += __shfl_down(s2[u], o, 64);
    }
  if ((tid & 63) == 0)
#pragma unroll
    for (int u = 0; u < 4; ++u) {
      redC[wid * 4 + u] = s1[u];
      redD[wid * 4 + u] = s2[u];
    }
  __syncthreads();

#pragma unroll
  for (int u = 0; u < 4; ++u) {
    const float S1 = redC[u] + redC[4 + u] + redC[8 + u] + redC[12 + u];
    const float S2 = redD[u] + redD[4 + u] + redD[8 + u] + redD[12 + u];
    if (valid) {
      const float logZ = __logf(S1);
      const float lp = y[u] - M1[u] - logZ;
      const float a = (S2 > 0.f) ? (e2[u] / S2) : 0.f;
      const long oidx = ((long)b * T1_ + t1base + u) * T2_ + t2;
      if (f) {
        ((float*)out)[N + oidx] = lp;
        ((float*)out)[oidx] = a;
      } else {
        ((bf16*)out)[N + oidx] = __float2bfloat16(lp);
        ((bf16*)out)[oidx] = __float2bfloat16(a);
      }
    }
  }
}

// ---------------------------------------------------------------------------
extern "C" void kernel_launch(void* const* d_in, const int* in_sizes, int n_in,
                              void* d_out, int out_size, void* d_ws, size_t ws_size,
                              hipStream_t stream) {
  const void* queries = d_in[0];
  const void* keys    = d_in[1];
  const void* mask    = d_in[3];
  const void* prior   = d_in[4];
  const void* kp_w1 = d_in[5];
  const void* kp_b1 = d_in[6];
  const void* kp_w2 = d_in[7];
  const void* kp_b2 = d_in[8];
  const void* qp_w1 = d_in[9];
  const void* qp_b1 = d_in[10];
  const void* qp_w2 = d_in[11];
  const void* qp_b2 = d_in[12];
  const void* qp_w3 = d_in[13];
  const void* qp_b3 = d_in[14];

  // ---- Workspace (R4 layout) ----
  float* keT   = (float*)d_ws;            // 128,000 f  [b][80][200] = -2k
  float* qeT   = keT + 128000;            // 512,000 f  [b][800][80]
  float* mf    = qeT + 512000;            //   1,600 f
  float* biasf = mf + 1600;               //   1,440 f
  float* kn    = biasf + 1440;            //   1,600 f  ||k||^2
  float* qn    = kn + 1600;               //   6,400 f  ||q||^2
  bf16* keysT    = (bf16*)(qn + 6400);    //   819,200
  bf16* queriesT = keysT + 819200;        //   512,000
  bf16* w1F      = queriesT + 512000;     // 1,572,864 (fragment-ordered)
  bf16* qw1T     = w1F + 1572864;         //    38,400
  bf16* kw2c     = qw1T + 38400;          //    81,920
  bf16* qw2c     = kw2c + 81920;          //    12,800
  bf16* qw3c     = qw2c + 12800;          //     6,400
  bf16* ke1T     = qw3c + 6400;           // 1,638,400
  bf16* qe1T     = ke1T + 1638400;        // 1,024,000

  float* b_k1 = biasf;          // 1024
  float* b_k2 = biasf + 1024;   // 80
  float* b_q1 = biasf + 1104;   // 160
  float* b_q2 = biasf + 1264;   // 80
  float* b_q3 = biasf + 1344;   // 80

  // Grid-barrier counter (far past used buffers; ws = 256 MB)
  int* bars = (int*)((char*)d_ws + (200u << 20));
  hipMemsetAsync(bars, 0, 64, stream);    // memset node: graph-capture legal

  // 1) fused prep (also zeroes kn); 2379 = 896+600+768+13+80+13+7+2
  k_prep<<<2379, 256, 0, stream>>>(
      queries, keys, mask,
      kp_w1, kp_b1, kp_w2, kp_b2,
      qp_w1, qp_b1, qp_w2, qp_b2, qp_w3, qp_b3,
      keysT, queriesT, w1F, qw1T, kw2c, qw2c, qw3c, biasf, mf, kn);

  // 2) fused conv1 + conv2f (grid barrier between phases)
  k_convs<<<NBLK, 256, 0, stream>>>(
      keysT, w1F, b_k1, ke1T, queriesT, qw1T, b_q1, qe1T,
      kw2c, b_k2, keT, kn, qw2c, b_q2, qw3c, b_q3, qeT, qn, bars);

  // 3) dist (2-phase reduction)
  k_dist<<<dim3(200, B_), 256, 0, stream>>>(
      qeT, keT, kn, qn, prior, mf, d_out, (const unsigned short*)queries);
}

// Round 9
// 175.359 us; speedup vs baseline: 1.1836x; 1.1836x over previous
//
#include <hip/hip_runtime.h>
#include <hip/hip_bf16.h>
#include <math.h>

// Problem dims (fixed by setup_inputs)
#define B_  8
#define CM  80
#define T1_ 800
#define CT  512
#define T2_ 200
#define CA  80

using bf16 = __hip_bfloat16;
typedef __attribute__((ext_vector_type(8))) short bf16x8;
typedef __attribute__((ext_vector_type(4))) float f32x4;

#define LDSW 56
#define LDSW2 72    // key-conv B row stride (BK=64 + pad)
#define LDSW3 168   // fused conv23 stage-1 row stride (K=160)
#define LDSW4 104   // fused conv23 stage-2 row stride (K=96 padded)

#define NBLK 256    // fused conv kernel grid: 256 blocks <= 256 CUs ->
                    // >=1 block/CU resident structurally (LDS 48.4KB<160,
                    // VGPR unconstrained); grid barrier cannot deadlock.

__device__ __forceinline__ float load_sel(const void* p, long idx, int isf32) {
  if (isf32) return ((const float*)p)[idx];
  return __bfloat162float(((const bf16*)p)[idx]);
}

__device__ __forceinline__ unsigned short f2bf(float x) {
  bf16 h = __float2bfloat16(x);
  return *reinterpret_cast<unsigned short*>(&h);
}

// Inline dtype probe (R8-R11 proven).
__device__ __forceinline__ int detect_f32(const unsigned short* q) {
  __shared__ int s_f;
  const int tid = threadIdx.x;
  if (tid < 64) {
    unsigned short u = q[2 * tid];
    int e = (u >> 7) & 0xFF;
    unsigned long long bal = __ballot(e < 100 || e > 154);
    if (tid == 0) s_f = (__popcll(bal) >= 16) ? 1 : 0;
  }
  __syncthreads();
  return s_f;
}

// Device-scope grid barrier (R2-validated). Counter zeroed by k_prep.
__device__ __forceinline__ void grid_bar(int* cnt) {
  __syncthreads();
  if (threadIdx.x == 0) {
    __threadfence();                       // release
    int arrived = atomicAdd(cnt, 1) + 1;
    if (arrived < NBLK) {
      while (atomicAdd(cnt, 0) < NBLK) __builtin_amdgcn_s_sleep(4);
    }
    __threadfence();                       // acquire
  }
  __syncthreads();
}

// ---------------------------------------------------------------------------
// Prep tasks (R4-proven).
// ---------------------------------------------------------------------------
__device__ void task_cvt_t(const void* X, bf16* XT, int f, int C, int T,
                           int id2, int tilesT, float* smem, int tid) {
  const int per_b = tilesT * ((C + 31) >> 5);
  const int b = id2 / per_b;
  const int r = id2 - b * per_b;
  const int ct = r / tilesT, tt = r - ct * tilesT;
  const int c0 = ct * 32, t0 = tt * 32;
  const int tx = tid & 31, trow = tid >> 5;
#pragma unroll
  for (int p = 0; p < 4; ++p) {
    const int cr = trow + 8 * p;
    if (c0 + cr < C && t0 + tx < T)
      smem[cr * 33 + tx] = load_sel(X, ((long)b * C + c0 + cr) * T + t0 + tx, f);
  }
  __syncthreads();
#pragma unroll
  for (int p = 0; p < 4; ++p) {
    const int tr = trow + 8 * p;
    if (t0 + tr < T && c0 + tx < C)
      XT[((long)b * T + t0 + tr) * C + c0 + tx] =
          __float2bfloat16(smem[tx * 33 + tr]);
  }
}

// kp_w1 -> MFMA-fragment-ordered w1F: [panel8][ks24][w2:2][mi:4][h:2][lane64][e8]
__device__ void task_wfrag(const void* W, bf16* WF, int f, int id2, int tid) {
  const int id = id2 * 256 + tid;            // 0 .. 196607
  const int l  = id & 63;
  int rest = id >> 6;                        // 0..3071
  const int h  = rest & 1; rest >>= 1;
  const int mi = rest & 3; rest >>= 2;
  const int w2 = rest & 1; rest >>= 1;
  const int ks = rest % 24;
  const int p  = rest / 24;
  const int co = p * 128 + w2 * 64 + mi * 16 + (l & 15);
  const int k0 = ks * 64 + h * 32 + (l >> 4) * 8;
  const int dk = k0 >> 9;
  const int ci = k0 & 511;
  const long sbase = ((long)co * 512 + ci) * 3 + dk;
  ushort4 u0, u1;
  u0.x = f2bf(load_sel(W, sbase + 0 * 3, f));
  u0.y = f2bf(load_sel(W, sbase + 1 * 3, f));
  u0.z = f2bf(load_sel(W, sbase + 2 * 3, f));
  u0.w = f2bf(load_sel(W, sbase + 3 * 3, f));
  u1.x = f2bf(load_sel(W, sbase + 4 * 3, f));
  u1.y = f2bf(load_sel(W, sbase + 5 * 3, f));
  u1.z = f2bf(load_sel(W, sbase + 6 * 3, f));
  u1.w = f2bf(load_sel(W, sbase + 7 * 3, f));
  *(ushort4*)(WF + (long)id * 8) = u0;
  *(ushort4*)(WF + (long)id * 8 + 4) = u1;
}

__device__ void task_wt3v(const void* W, bf16* WT, int f, int Co, int Ci,
                          int id2, int tid) {
  const int i = id2 * 256 + tid;
  const int g4 = Ci >> 2;
  if (i >= Co * g4) return;
  const int co = i / g4, ci = (i - co * g4) * 4;
  const long sbase = ((long)co * Ci + ci) * 3;
  float w[12];
  if (f) {
    const float4* s = (const float4*)((const float*)W + sbase);
    float4 f0 = s[0], f1 = s[1], f2 = s[2];
    w[0]=f0.x; w[1]=f0.y; w[2]=f0.z; w[3]=f0.w; w[4]=f1.x; w[5]=f1.y;
    w[6]=f1.z; w[7]=f1.w; w[8]=f2.x; w[9]=f2.y; w[10]=f2.z; w[11]=f2.w;
  } else {
#pragma unroll
    for (int j = 0; j < 12; ++j) w[j] = load_sel(W, sbase + j, 0);
  }
#pragma unroll
  for (int dk = 0; dk < 3; ++dk) {
    ushort4 u;
    u.x = f2bf(w[0 * 3 + dk]); u.y = f2bf(w[1 * 3 + dk]);
    u.z = f2bf(w[2 * 3 + dk]); u.w = f2bf(w[3 * 3 + dk]);
    *(ushort4*)(WT + ((long)dk * Co + co) * Ci + ci) = u;
  }
}

__device__ void task_cvtv(const void* W, bf16* O, int f, int n, int id2, int tid) {
  const int i = (id2 * 256 + tid) * 4;
  if (i >= n) return;
  ushort4 u;
  if (f) {
    float4 v = *(const float4*)((const float*)W + i);
    u.x = f2bf(v.x); u.y = f2bf(v.y); u.z = f2bf(v.z); u.w = f2bf(v.w);
  } else {
    u.x = f2bf(load_sel(W, i, 0));     u.y = f2bf(load_sel(W, i + 1, 0));
    u.z = f2bf(load_sel(W, i + 2, 0)); u.w = f2bf(load_sel(W, i + 3, 0));
  }
  *(ushort4*)(O + i) = u;
}

__global__ __launch_bounds__(256) void k_prep(
    const void* __restrict__ queries, const void* __restrict__ keys,
    const void* __restrict__ mask,
    const void* __restrict__ kp_w1, const void* __restrict__ kp_b1,
    const void* __restrict__ kp_w2, const void* __restrict__ kp_b2,
    const void* __restrict__ qp_w1, const void* __restrict__ qp_b1,
    const void* __restrict__ qp_w2, const void* __restrict__ qp_b2,
    const void* __restrict__ qp_w3, const void* __restrict__ qp_b3,
    bf16* __restrict__ keysT, bf16* __restrict__ queriesT,
    bf16* __restrict__ w1F, bf16* __restrict__ qw1T,
    bf16* __restrict__ kw2c, bf16* __restrict__ qw2c, bf16* __restrict__ qw3c,
    float* __restrict__ biasf, float* __restrict__ mf, float* __restrict__ kn,
    int* __restrict__ bars) {
  __shared__ float smem[32 * 33];
  const int tid = threadIdx.x;
  const int f = detect_f32((const unsigned short*)queries);
  int id = blockIdx.x;

  if (id < 896) { task_cvt_t(keys, keysT, f, CT, T2_, id, 7, smem, tid); return; }
  id -= 896;
  if (id < 600) { task_cvt_t(queries, queriesT, f, CM, T1_, id, 25, smem, tid); return; }
  id -= 600;
  if (id < 768) { task_wfrag(kp_w1, w1F, f, id, tid); return; }
  id -= 768;
  if (id < 13) { task_wt3v(qp_w1, qw1T, f, 160, CM, id, tid); return; }
  id -= 13;
  if (id < 80) { task_cvtv(kp_w2, kw2c, f, 80 * 1024, id, tid); return; }
  id -= 80;
  if (id < 13) { task_cvtv(qp_w2, qw2c, f, 80 * 160, id, tid); return; }
  id -= 13;
  if (id < 7) { task_cvtv(qp_w3, qw3c, f, 80 * 80, id, tid); return; }
  id -= 7;

  if (id == 0) {
    for (int i = tid; i < 1424; i += 256) {
      float v;
      if (i < 1024)      v = load_sel(kp_b1, i, f);
      else if (i < 1104) v = load_sel(kp_b2, i - 1024, f);
      else if (i < 1264) v = load_sel(qp_b1, i - 1104, f);
      else if (i < 1344) v = load_sel(qp_b2, i - 1264, f);
      else               v = load_sel(qp_b3, i - 1344, f);
      biasf[i] = v;
    }
    // zero key-norm accumulator + grid-barrier counters (replaces memset node)
    for (int i = tid; i < B_ * T2_; i += 256) kn[i] = 0.f;
    if (tid < 16) bars[tid] = 0;
    return;
  }

  // mask normalize (R2-proven format detection)
  {
    int* s_fmt = (int*)smem;
    const int nmask = B_ * T2_;
    if (tid == 0) s_fmt[0] = 1;
    __syncthreads();
    const unsigned int* wi = (const unsigned int*)mask;
    const int nw = nmask / 4;
    int pri = 0;
    for (int i = tid; i < nw; i += 256) {
      unsigned int w = wi[i];
      if (w == 0u || w == 1u) continue;
      if (w == 0x3F803F80u || w == 0x00003F80u) { pri = max(pri, 2); continue; }
      if (w == 0x3F800000u) continue;
      unsigned int b0 = w & 0xFFu, b1 = (w >> 8) & 0xFFu,
                   b2 = (w >> 16) & 0xFFu, b3 = (w >> 24) & 0xFFu;
      if (b0 <= 1u && b1 <= 1u && b2 <= 1u && b3 <= 1u) pri = max(pri, 3);
      else pri = max(pri, 2);
    }
    if (pri) atomicMax(&s_fmt[0], pri);
    __syncthreads();
    const int fmt = s_fmt[0];
    for (int i = tid; i < nmask; i += 256) {
      int m;
      if (fmt == 3)      m = ((const unsigned char*)mask)[i] != 0;
      else if (fmt == 2) m = ((const unsigned short*)mask)[i] != 0;
      else               m = (wi[i] != 0u);
      mf[i] = (float)m;
    }
  }
}

// ---------------------------------------------------------------------------
// Generic conv tile, BK=32 (R4-proven) + reg-prefetch.
// outmode: 0 = bf16 [n][Cout]; 1 = fp32 [n][Cout];
// 2 = keT [b][80][200] = -2v + atomicAdd v^2 into Y2.
// ---------------------------------------------------------------------------
__device__ void conv_tile(
    const bf16* __restrict__ XT, const bf16* __restrict__ WT,
    const float* __restrict__ bias, void* __restrict__ Y,
    int Cin, int Cout, int T, int KW, int pad, int relu, int outmode,
    int m0, int n0, short* As, short* Bs, float* Y2 = nullptr) {
  const int K = Cin * KW;
  const int tid = threadIdx.x;
  const int wave = tid >> 6;
  const int lane = tid & 63;

  const int row = tid >> 2;
  const int koff = (tid & 3) * 8;
  const int n = n0 + row;
  const int bb = n / T;
  const int t = n - bb * T;

  const int wm = (wave >> 1) * 32;
  const int wn = (wave & 1) * 32;
  const int fm = lane & 15;
  const int quad = lane >> 4;

  f32x4 acc[2][2] = {};

  const short* ap0 = As + (wm + fm) * LDSW + quad * 8;
  const short* bp0 = Bs + (wn + fm) * LDSW + quad * 8;

  auto loadA = [&](int k0) -> uint4 {
    const int k = k0 + koff;
    const int m = m0 + row;
    uint4 v = {0u, 0u, 0u, 0u};
    if (m < Cout && k < K) {
      const int dk = k / Cin;
      const int ci = k - dk * Cin;
      v = *(const uint4*)(WT + ((long)dk * Cout + m) * Cin + ci);
    }
    return v;
  };
  auto loadB = [&](int k0) -> uint4 {
    const int k = k0 + koff;
    uint4 v = {0u, 0u, 0u, 0u};
    if (k < K) {
      const int dk = k / Cin;
      const int ci = k - dk * Cin;
      const int tt = t + dk - pad;
      if (tt >= 0 && tt < T)
        v = *(const uint4*)(XT + ((long)bb * T + tt) * Cin + ci);
    }
    return v;
  };

  uint4 va = loadA(0);
  uint4 vb = loadB(0);

  for (int k0 = 0; k0 < K; k0 += 32) {
    *(uint4*)(As + row * LDSW + koff) = va;
    *(uint4*)(Bs + row * LDSW + koff) = vb;
    if (k0 + 32 < K) {
      va = loadA(k0 + 32);
      vb = loadB(k0 + 32);
    }
    __syncthreads();
    {
      bf16x8 a0 = *(const bf16x8*)(ap0);
      bf16x8 a1 = *(const bf16x8*)(ap0 + 16 * LDSW);
      bf16x8 b0 = *(const bf16x8*)(bp0);
      bf16x8 b1 = *(const bf16x8*)(bp0 + 16 * LDSW);
      acc[0][0] = __builtin_amdgcn_mfma_f32_16x16x32_bf16(a0, b0, acc[0][0], 0, 0, 0);
      acc[0][1] = __builtin_amdgcn_mfma_f32_16x16x32_bf16(a0, b1, acc[0][1], 0, 0, 0);
      acc[1][0] = __builtin_amdgcn_mfma_f32_16x16x32_bf16(a1, b0, acc[1][0], 0, 0, 0);
      acc[1][1] = __builtin_amdgcn_mfma_f32_16x16x32_bf16(a1, b1, acc[1][1], 0, 0, 0);
    }
    __syncthreads();
  }

#pragma unroll
  for (int mi = 0; mi < 2; ++mi) {
    const int mrow = m0 + wm + mi * 16 + quad * 4;
    if (mrow >= Cout) continue;
    float bi[4];
#pragma unroll
    for (int r = 0; r < 4; ++r) bi[r] = bias[mrow + r];
#pragma unroll
    for (int ni = 0; ni < 2; ++ni) {
      const int ncol = n0 + wn + ni * 16 + fm;
      float o[4];
#pragma unroll
      for (int r = 0; r < 4; ++r) {
        float v = acc[mi][ni][r] + bi[r];
        if (relu) v = fmaxf(v, 0.f);
        o[r] = v;
      }
      if (outmode == 0) {
        ushort4 u;
        u.x = f2bf(o[0]); u.y = f2bf(o[1]); u.z = f2bf(o[2]); u.w = f2bf(o[3]);
        *(ushort4*)((bf16*)Y + (long)ncol * Cout + mrow) = u;
      } else if (outmode == 1) {
        *(float4*)((float*)Y + (long)ncol * Cout + mrow) =
            make_float4(o[0], o[1], o[2], o[3]);
      } else {
        // keT [b][Cout][T] = -2v, channel-major for coalesced dist reads
        const int bb2 = ncol / T;
        const int tloc = ncol - bb2 * T;
        float s4 = 0.f;
#pragma unroll
        for (int r = 0; r < 4; ++r) {
          ((float*)Y)[((long)bb2 * Cout + mrow + r) * T + tloc] = -2.f * o[r];
          s4 = fmaf(o[r], o[r], s4);
        }
        atomicAdd(&Y2[ncol], s4);
      }
    }
  }
}

// ---------------------------------------------------------------------------
// Key-conv1, 128x64 tile, BK=64 (R7-proven): A direct from w1F with
// ping-pong prefetch, B reg-prefetch -> LDS per step.
// ---------------------------------------------------------------------------
__device__ void conv_key128(
    const bf16* __restrict__ XT, const bf16* __restrict__ WF,
    const float* __restrict__ bias, bf16* __restrict__ Y,
    int panel, int n0, short* Bs) {
  const int Cin = CT, Cout = 1024, T = T2_;
  const int tid = threadIdx.x;
  const int wave = tid >> 6;
  const int lane = tid & 63;
  const int m0 = panel * 128;

  const int rowb = tid >> 2;
  const int nb = n0 + rowb;
  const int bbb = nb / T;
  const int tb = nb - bbb * T;
  const int kcb = (tid & 3) * 16;

  const int w2 = wave >> 1;
  const int wn = (wave & 1) * 32;
  const int fm = lane & 15;
  const int quad = lane >> 4;

  f32x4 acc[4][2] = {};
  const short* bp0 = Bs + (wn + fm) * LDSW2 + quad * 8;

  uint4 vb0, vb1;
  auto loadB = [&](int k0) {
    const int dk = k0 >> 9;
    const int ci0 = k0 & 511;
    const int tt = tb + dk - 1;
    if (tt >= 0 && tt < T) {
      const bf16* src = XT + ((long)bbb * T + tt) * Cin + ci0 + kcb;
      vb0 = *(const uint4*)(src);
      vb1 = *(const uint4*)(src + 8);
    } else {
      uint4 z = {0u, 0u, 0u, 0u};
      vb0 = z; vb1 = z;
    }
  };

  bf16x8 a0c[4], a1c[4], a0n[4], a1n[4];
  auto loadA = [&](int ks, bf16x8 d0[4], bf16x8 d1[4]) {
    const long abase = ((((long)panel * 24 + ks) * 2 + w2) * 4096) + lane * 8;
#pragma unroll
    for (int mi = 0; mi < 4; ++mi) {
      d0[mi] = *(const bf16x8*)(WF + abase + (mi * 2 + 0) * 512);
      d1[mi] = *(const bf16x8*)(WF + abase + (mi * 2 + 1) * 512);
    }
  };

  loadB(0);
  loadA(0, a0c, a1c);

  for (int k0 = 0; k0 < 1536; k0 += 64) {
    {
      short* dstb = Bs + rowb * LDSW2 + kcb;
      *(uint4*)(dstb) = vb0;
      *(uint4*)(dstb + 8) = vb1;
    }
    const bool more = (k0 + 64 < 1536);
    if (more) {
      loadB(k0 + 64);
      loadA((k0 >> 6) + 1, a0n, a1n);
    }
    __syncthreads();
    {
      bf16x8 b00 = *(const bf16x8*)(bp0);
      bf16x8 b01 = *(const bf16x8*)(bp0 + 16 * LDSW2);
#pragma unroll
      for (int mi = 0; mi < 4; ++mi) {
        acc[mi][0] = __builtin_amdgcn_mfma_f32_16x16x32_bf16(a0c[mi], b00, acc[mi][0], 0, 0, 0);
        acc[mi][1] = __builtin_amdgcn_mfma_f32_16x16x32_bf16(a0c[mi], b01, acc[mi][1], 0, 0, 0);
      }
      bf16x8 b10 = *(const bf16x8*)(bp0 + 32);
      bf16x8 b11 = *(const bf16x8*)(bp0 + 16 * LDSW2 + 32);
#pragma unroll
      for (int mi = 0; mi < 4; ++mi) {
        acc[mi][0] = __builtin_amdgcn_mfma_f32_16x16x32_bf16(a1c[mi], b10, acc[mi][0], 0, 0, 0);
        acc[mi][1] = __builtin_amdgcn_mfma_f32_16x16x32_bf16(a1c[mi], b11, acc[mi][1], 0, 0, 0);
      }
    }
    __syncthreads();
    if (more) {
#pragma unroll
      for (int mi = 0; mi < 4; ++mi) { a0c[mi] = a0n[mi]; a1c[mi] = a1n[mi]; }
    }
  }

#pragma unroll
  for (int mi = 0; mi < 4; ++mi) {
    const int mrow = m0 + w2 * 64 + mi * 16 + quad * 4;
    float bi[4];
#pragma unroll
    for (int r = 0; r < 4; ++r) bi[r] = bias[mrow + r];
#pragma unroll
    for (int ni = 0; ni < 2; ++ni) {
      const int ncol = n0 + wn + ni * 16 + fm;
      const long base = (long)ncol * Cout + mrow;
      ushort4 u;
      u.x = f2bf(fmaxf(acc[mi][ni][0] + bi[0], 0.f));
      u.y = f2bf(fmaxf(acc[mi][ni][1] + bi[1], 0.f));
      u.z = f2bf(fmaxf(acc[mi][ni][2] + bi[2], 0.f));
      u.w = f2bf(fmaxf(acc[mi][ni][3] + bi[3], 0.f));
      *(ushort4*)(Y + base) = u;
    }
  }
}

// ---------------------------------------------------------------------------
// Fused query conv2+conv3 (R4-proven) + qn (||q||^2) epilogue.
// ---------------------------------------------------------------------------
__device__ void conv23_tile(
    const bf16* __restrict__ qe1T, const bf16* __restrict__ qw2c,
    const float* __restrict__ b_q2, const bf16* __restrict__ qw3c,
    const float* __restrict__ b_q3, float* __restrict__ qeT,
    float* __restrict__ qn, int n0, short* smem) {
  short* sIn = smem;
  short* sW2 = smem + 64 * LDSW3;
  short* sC  = smem;
  short* sW3 = smem + 64 * LDSW3;
  const int tid = threadIdx.x;
  const int wave = tid >> 6;
  const int lane = tid & 63;
  const int fm = lane & 15;
  const int quad = lane >> 4;

#pragma unroll
  for (int c = tid; c < 1280; c += 256) {
    const int row = c / 20, kc = (c - row * 20) * 8;
    uint4 v = *(const uint4*)(qe1T + (long)(n0 + row) * 160 + kc);
    *(uint4*)(sIn + row * LDSW3 + kc) = v;
  }
  for (int c = tid; c < 1600; c += 256) {
    const int row = c / 20, kc = (c - row * 20) * 8;
    uint4 v = *(const uint4*)(qw2c + (long)row * 160 + kc);
    *(uint4*)(sW2 + row * LDSW3 + kc) = v;
  }
  __syncthreads();

  f32x4 acc1[5] = {};
#pragma unroll
  for (int ks = 0; ks < 5; ++ks) {
    bf16x8 b = *(const bf16x8*)(sIn + (16 * wave + fm) * LDSW3 + ks * 32 + quad * 8);
#pragma unroll
    for (int mt = 0; mt < 5; ++mt) {
      bf16x8 a = *(const bf16x8*)(sW2 + (16 * mt + fm) * LDSW3 + ks * 32 + quad * 8);
      acc1[mt] = __builtin_amdgcn_mfma_f32_16x16x32_bf16(a, b, acc1[mt], 0, 0, 0);
    }
  }
  __syncthreads();

#pragma unroll
  for (int mt = 0; mt < 5; ++mt) {
    const int ch = 16 * mt + quad * 4;
    const float4 b2 = *(const float4*)(b_q2 + ch);
    ushort4 u;
    u.x = f2bf(fmaxf(acc1[mt][0] + b2.x, 0.f));
    u.y = f2bf(fmaxf(acc1[mt][1] + b2.y, 0.f));
    u.z = f2bf(fmaxf(acc1[mt][2] + b2.z, 0.f));
    u.w = f2bf(fmaxf(acc1[mt][3] + b2.w, 0.f));
    *(ushort4*)(sC + (16 * wave + fm) * LDSW4 + ch) = u;
  }
  if (tid < 128) {
    const int row = tid >> 1, off = 80 + (tid & 1) * 8;
    uint4 z = {0u, 0u, 0u, 0u};
    *(uint4*)(sC + row * LDSW4 + off) = z;
  }
  for (int c = tid; c < 800; c += 256) {
    const int row = c / 10, kc = (c - row * 10) * 8;
    uint4 v = *(const uint4*)(qw3c + (long)row * 80 + kc);
    *(uint4*)(sW3 + row * LDSW4 + kc) = v;
  }
  if (tid < 160) {
    const int row = tid >> 1, off = 80 + (tid & 1) * 8;
    uint4 z = {0u, 0u, 0u, 0u};
    *(uint4*)(sW3 + row * LDSW4 + off) = z;
  }
  __syncthreads();

  f32x4 acc2[5] = {};
#pragma unroll
  for (int ks = 0; ks < 3; ++ks) {
    bf16x8 b = *(const bf16x8*)(sC + (16 * wave + fm) * LDSW4 + ks * 32 + quad * 8);
#pragma unroll
    for (int mt = 0; mt < 5; ++mt) {
      bf16x8 a = *(const bf16x8*)(sW3 + (16 * mt + fm) * LDSW4 + ks * 32 + quad * 8);
      acc2[mt] = __builtin_amdgcn_mfma_f32_16x16x32_bf16(a, b, acc2[mt], 0, 0, 0);
    }
  }

  const int pos = n0 + 16 * wave + fm;
  float p = 0.f;
#pragma unroll
  for (int mt = 0; mt < 5; ++mt) {
    const int ch = 16 * mt + quad * 4;
    const float4 b3 = *(const float4*)(b_q3 + ch);
    float4 o = make_float4(acc2[mt][0] + b3.x, acc2[mt][1] + b3.y,
                           acc2[mt][2] + b3.z, acc2[mt][3] + b3.w);
    p = fmaf(o.x, o.x, p); p = fmaf(o.y, o.y, p);
    p = fmaf(o.z, o.z, p); p = fmaf(o.w, o.w, p);
    *(float4*)(qeT + (long)pos * CA + ch) = o;
  }
  p += __shfl_xor(p, 16, 64);
  p += __shfl_xor(p, 32, 64);
  if (quad == 0) qn[pos] = p;
}

// ---------------------------------------------------------------------------
// Fused conv kernel v2: grid 256 (1 block/CU structural residency, VGPR
// UNCONSTRAINED -> no spill). Phase 1 = conv1 (500 tasks, 2-deep loop),
// grid barrier, phase 2 = conv2f (150 tasks).
// ---------------------------------------------------------------------------
__global__ __launch_bounds__(256) void k_convs(
    const bf16* __restrict__ keysT, const bf16* __restrict__ w1F,
    const float* __restrict__ b_k1, bf16* __restrict__ ke1T,
    const bf16* __restrict__ queriesT, const bf16* __restrict__ qw1T,
    const float* __restrict__ b_q1, bf16* __restrict__ qe1T,
    const bf16* __restrict__ kw2c, const float* __restrict__ b_k2,
    float* __restrict__ keT, float* __restrict__ kn,
    const bf16* __restrict__ qw2c, const float* __restrict__ b_q2,
    const bf16* __restrict__ qw3c, const float* __restrict__ b_q3,
    float* __restrict__ qeT, float* __restrict__ qn,
    int* __restrict__ bars) {
  __shared__ __align__(16) short smem[144 * LDSW3];   // 48.4 KB, all phases
  const int j = blockIdx.x;

  // ---- Phase 1: conv1, tasks t = j, j+256 (256%8==0 keeps panel->XCD) ----
  for (int t = j; t < 500; t += NBLK) {
    if (t < 200) {
      conv_key128(keysT, w1F, b_k1, ke1T, t & 7, (t >> 3) * 64, smem);
    } else {
      const int q = t - 200;
      conv_tile(queriesT, qw1T, b_q1, qe1T, CM, 160, T1_, 3, 1, 1, 0,
                (q / 100) * 64, (q % 100) * 64, smem, smem + 64 * LDSW);
    }
    __syncthreads();   // smem reuse across loop iterations
  }

  grid_bar(&bars[0]);

  // ---- Phase 2: conv2f (150 tasks on blocks 0..149) ----
  if (j < 50) {
    conv_tile(ke1T, kw2c, b_k2, keT, 1024, CA, T2_, 1, 0, 0, 2,
              (j / 25) * 64, (j % 25) * 64, smem, smem + 64 * LDSW, kn);
  } else if (j < 150) {
    conv23_tile(qe1T, qw2c, b_q2, qw3c, b_q3, qeT, qn, (j - 50) * 64, smem);
  }
}

// ---------------------------------------------------------------------------
// dist: 4 t1-rows per block, 2-phase reduction (R7-proven).
// ---------------------------------------------------------------------------
__global__ __launch_bounds__(256) void k_dist(
    const float* __restrict__ qeT, const float* __restrict__ keT2,
    const float* __restrict__ kn, const float* __restrict__ qn,
    const void* __restrict__ prior, const float* __restrict__ mf,
    void* __restrict__ out, const unsigned short* __restrict__ qprobe) {
  __shared__ float sq[4 * CA];
  __shared__ float sqn[4];
  __shared__ float redA[16], redB[16], redC[16], redD[16];
  const int f = detect_f32(qprobe);
  const int b = blockIdx.y;
  const int t1base = blockIdx.x * 4;
  const int tid = threadIdx.x;
  const int wid = tid >> 6;

  const int t2 = tid;
  const bool valid = (t2 < T2_);
  const long N = (long)B_ * T1_ * T2_;

  float pr[4] = {0.f, 0.f, 0.f, 0.f};
  float mval = 1.f;
  if (valid) {
#pragma unroll
    for (int u = 0; u < 4; ++u)
      pr[u] = load_sel(prior, ((long)b * T1_ + t1base + u) * T2_ + t2, f);
    mval = mf[b * T2_ + t2];
  }

  for (int i = tid; i < 4 * CA; i += 256) {
    int u = i / CA, c = i - u * CA;
    sq[i] = qeT[((long)b * T1_ + t1base + u) * CA + c];
  }
  if (tid < 4) sqn[tid] = qn[b * T1_ + t1base + tid];
  __syncthreads();

  float x[4] = {-INFINITY, -INFINITY, -INFINITY, -INFINITY};
  if (valid) {
    const float* kp = keT2 + (long)b * CA * T2_ + t2;
    const float knv = kn[b * T2_ + t2];
    float a0 = 0.f, a1 = 0.f, a2 = 0.f, a3 = 0.f;
#pragma unroll 2
    for (int j = 0; j < CA; j += 4) {
      const float4 q0 = *(const float4*)(sq + 0 * CA + j);
      const float4 q1 = *(const float4*)(sq + 1 * CA + j);
      const float4 q2 = *(const float4*)(sq + 2 * CA + j);
      const float4 q3 = *(const float4*)(sq + 3 * CA + j);
      const float k0v = kp[(j + 0) * T2_];
      const float k1v = kp[(j + 1) * T2_];
      const float k2v = kp[(j + 2) * T2_];
      const float k3v = kp[(j + 3) * T2_];
      a0 = fmaf(k0v, q0.x, a0); a0 = fmaf(k1v, q0.y, a0);
      a0 = fmaf(k2v, q0.z, a0); a0 = fmaf(k3v, q0.w, a0);
      a1 = fmaf(k0v, q1.x, a1); a1 = fmaf(k1v, q1.y, a1);
      a1 = fmaf(k2v, q1.z, a1); a1 = fmaf(k3v, q1.w, a1);
      a2 = fmaf(k0v, q2.x, a2); a2 = fmaf(k1v, q2.y, a2);
      a2 = fmaf(k2v, q2.z, a2); a2 = fmaf(k3v, q2.w, a2);
      a3 = fmaf(k0v, q3.x, a3); a3 = fmaf(k1v, q3.y, a3);
      a3 = fmaf(k2v, q3.z, a3); a3 = fmaf(k3v, q3.w, a3);
    }
    x[0] = -0.0005f * (a0 + sqn[0] + knv);
    x[1] = -0.0005f * (a1 + sqn[1] + knv);
    x[2] = -0.0005f * (a2 + sqn[2] + knv);
    x[3] = -0.0005f * (a3 + sqn[3] + knv);
  }

  float y[4], ym[4];
#pragma unroll
  for (int u = 0; u < 4; ++u) {
    if (valid) {
      const float lpr = __logf(fmaxf(pr[u], 0.f) + 1e-8f);
      y[u] = x[u] + lpr;
    } else {
      y[u] = -INFINITY;
    }
    ym[u] = (valid && mval == 0.f) ? y[u] : -INFINITY;
  }

  // --- phase A: max(x) and maskedmax(y) ---
  float m1[4], m2[4];
#pragma unroll
  for (int u = 0; u < 4; ++u) { m1[u] = x[u]; m2[u] = ym[u]; }
#pragma unroll
  for (int o = 32; o > 0; o >>= 1)
#pragma unroll
    for (int u = 0; u < 4; ++u) {
      m1[u] = fmaxf(m1[u], __shfl_down(m1[u], o, 64));
      m2[u] = fmaxf(m2[u], __shfl_down(m2[u], o, 64));
    }
  if ((tid & 63) == 0)
#pragma unroll
    for (int u = 0; u < 4; ++u) {
      redA[wid * 4 + u] = m1[u];
      redB[wid * 4 + u] = m2[u];
    }
  __syncthreads();
  float M1[4], M2[4];
#pragma unroll
  for (int u = 0; u < 4; ++u) {
    M1[u] = fmaxf(fmaxf(redA[u], redA[4 + u]), fmaxf(redA[8 + u], redA[12 + u]));
    M2[u] = fmaxf(fmaxf(redB[u], redB[4 + u]), fmaxf(redB[8 + u], redB[12 + u]));
  }

  // --- phase B: both exp-sums ---
  float e2[4], s1[4], s2[4];
#pragma unroll
  for (int u = 0; u < 4; ++u) {
    s1[u] = (x[u] == -INFINITY) ? 0.f : __expf(x[u] - M1[u]);
    e2[u] = (ym[u] == -INFINITY) ? 0.f : __expf(ym[u] - M2[u]);
    s2[u] = e2[u];
  }
#pragma unroll
  for (int o = 32; o > 0; o >>= 1)
#pragma unroll
    for (int u = 0; u < 4; ++u) {
      s1[u] += __shfl_down(s1[u], o, 64);
      s2[u] += __shfl_down(s2[u], o, 64);
    }
  if ((tid & 63) == 0)
#pragma unroll
    for (int u = 0; u < 4; ++u) {
      redC[wid * 4 + u] = s1[u];
      redD[wid * 4 + u] = s2[u];
    }
  __syncthreads();

#pragma unroll
  for (int u = 0; u < 4; ++u) {
    const float S1 = redC[u] + redC[4 + u] + redC[8 + u] + redC[12 + u];
    const float S2 = redD[u] + redD[4 + u] + redD[8 + u] + redD[12 + u];
    if (valid) {
      const float logZ = __logf(S1);
      const float lp = y[u] - M1[u] - logZ;
      const float a = (S2 > 0.f) ? (e2[u] / S2) : 0.f;
      const long oidx = ((long)b * T1_ + t1base + u) * T2_ + t2;
      if (f) {
        ((float*)out)[N + oidx] = lp;
        ((float*)out)[oidx] = a;
      } else {
        ((bf16*)out)[N + oidx] = __float2bfloat16(lp);
        ((bf16*)out)[oidx] = __float2bfloat16(a);
      }
    }
  }
}

// ---------------------------------------------------------------------------
extern "C" void kernel_launch(void* const* d_in, const int* in_sizes, int n_in,
                              void* d_out, int out_size, void* d_ws, size_t ws_size,
                              hipStream_t stream) {
  const void* queries = d_in[0];
  const void* keys    = d_in[1];
  const void* mask    = d_in[3];
  const void* prior   = d_in[4];
  const void* kp_w1 = d_in[5];
  const void* kp_b1 = d_in[6];
  const void* kp_w2 = d_in[7];
  const void* kp_b2 = d_in[8];
  const void* qp_w1 = d_in[9];
  const void* qp_b1 = d_in[10];
  const void* qp_w2 = d_in[11];
  const void* qp_b2 = d_in[12];
  const void* qp_w3 = d_in[13];
  const void* qp_b3 = d_in[14];

  // ---- Workspace (R4 layout) ----
  float* keT   = (float*)d_ws;            // 128,000 f  [b][80][200] = -2k
  float* qeT   = keT + 128000;            // 512,000 f  [b][800][80]
  float* mf    = qeT + 512000;            //   1,600 f
  float* biasf = mf + 1600;               //   1,440 f
  float* kn    = biasf + 1440;            //   1,600 f  ||k||^2
  float* qn    = kn + 1600;               //   6,400 f  ||q||^2
  bf16* keysT    = (bf16*)(qn + 6400);    //   819,200
  bf16* queriesT = keysT + 819200;        //   512,000
  bf16* w1F      = queriesT + 512000;     // 1,572,864 (fragment-ordered)
  bf16* qw1T     = w1F + 1572864;         //    38,400
  bf16* kw2c     = qw1T + 38400;          //    81,920
  bf16* qw2c     = kw2c + 81920;          //    12,800
  bf16* qw3c     = qw2c + 12800;          //     6,400
  bf16* ke1T     = qw3c + 6400;           // 1,638,400
  bf16* qe1T     = ke1T + 1638400;        // 1,024,000

  float* b_k1 = biasf;          // 1024
  float* b_k2 = biasf + 1024;   // 80
  float* b_q1 = biasf + 1104;   // 160
  float* b_q2 = biasf + 1264;   // 80
  float* b_q3 = biasf + 1344;   // 80

  // Grid-barrier counter (far past used buffers; zeroed by k_prep)
  int* bars = (int*)((char*)d_ws + (200u << 20));

  // 1) fused prep (also zeroes kn + bars); 2379 blocks
  k_prep<<<2379, 256, 0, stream>>>(
      queries, keys, mask,
      kp_w1, kp_b1, kp_w2, kp_b2,
      qp_w1, qp_b1, qp_w2, qp_b2, qp_w3, qp_b3,
      keysT, queriesT, w1F, qw1T, kw2c, qw2c, qw3c, biasf, mf, kn, bars);

  // 2) fused conv1 + conv2f (grid barrier; 256 blocks, unconstrained VGPR)
  k_convs<<<NBLK, 256, 0, stream>>>(
      keysT, w1F, b_k1, ke1T, queriesT, qw1T, b_q1, qe1T,
      kw2c, b_k2, keT, kn, qw2c, b_q2, qw3c, b_q3, qeT, qn, bars);

  // 3) dist (2-phase reduction)
  k_dist<<<dim3(200, B_), 256, 0, stream>>>(
      qeT, keT, kn, qn, prior, mf, d_out, (const unsigned short*)queries);
}

// Round 10
// 147.104 us; speedup vs baseline: 1.4110x; 1.1921x over previous
//
#include <hip/hip_runtime.h>
#include <hip/hip_bf16.h>
#include <math.h>

// Problem dims (fixed by setup_inputs)
#define B_  8
#define CM  80
#define T1_ 800
#define CT  512
#define T2_ 200
#define CA  80

using bf16 = __hip_bfloat16;
typedef __attribute__((ext_vector_type(8))) short bf16x8;
typedef __attribute__((ext_vector_type(4))) float f32x4;

#define LDSW 56
#define LDSW2B 136  // key-conv B row stride: BK=128 cols + 8 pad (68 dw = 4 mod 32)
#define LDSW3 168   // fused conv23 stage-1 row stride (K=160)
#define LDSW4 104   // fused conv23 stage-2 row stride (K=96 padded)

__device__ __forceinline__ float load_sel(const void* p, long idx, int isf32) {
  if (isf32) return ((const float*)p)[idx];
  return __bfloat162float(((const bf16*)p)[idx]);
}

__device__ __forceinline__ unsigned short f2bf(float x) {
  bf16 h = __float2bfloat16(x);
  return *reinterpret_cast<unsigned short*>(&h);
}

// Inline dtype probe (R8-R11 proven).
__device__ __forceinline__ int detect_f32(const unsigned short* q) {
  __shared__ int s_f;
  const int tid = threadIdx.x;
  if (tid < 64) {
    unsigned short u = q[2 * tid];
    int e = (u >> 7) & 0xFF;
    unsigned long long bal = __ballot(e < 100 || e > 154);
    if (tid == 0) s_f = (__popcll(bal) >= 16) ? 1 : 0;
  }
  __syncthreads();
  return s_f;
}

// ---------------------------------------------------------------------------
// Prep tasks (R4-proven).
// ---------------------------------------------------------------------------
__device__ void task_cvt_t(const void* X, bf16* XT, int f, int C, int T,
                           int id2, int tilesT, float* smem, int tid) {
  const int per_b = tilesT * ((C + 31) >> 5);
  const int b = id2 / per_b;
  const int r = id2 - b * per_b;
  const int ct = r / tilesT, tt = r - ct * tilesT;
  const int c0 = ct * 32, t0 = tt * 32;
  const int tx = tid & 31, trow = tid >> 5;
#pragma unroll
  for (int p = 0; p < 4; ++p) {
    const int cr = trow + 8 * p;
    if (c0 + cr < C && t0 + tx < T)
      smem[cr * 33 + tx] = load_sel(X, ((long)b * C + c0 + cr) * T + t0 + tx, f);
  }
  __syncthreads();
#pragma unroll
  for (int p = 0; p < 4; ++p) {
    const int tr = trow + 8 * p;
    if (t0 + tr < T && c0 + tx < C)
      XT[((long)b * T + t0 + tr) * C + c0 + tx] =
          __float2bfloat16(smem[tx * 33 + tr]);
  }
}

// kp_w1 -> MFMA-fragment-ordered w1F: [panel8][ks24][w2:2][mi:4][h:2][lane64][e8]
__device__ void task_wfrag(const void* W, bf16* WF, int f, int id2, int tid) {
  const int id = id2 * 256 + tid;            // 0 .. 196607
  const int l  = id & 63;
  int rest = id >> 6;                        // 0..3071
  const int h  = rest & 1; rest >>= 1;
  const int mi = rest & 3; rest >>= 2;
  const int w2 = rest & 1; rest >>= 1;
  const int ks = rest % 24;
  const int p  = rest / 24;
  const int co = p * 128 + w2 * 64 + mi * 16 + (l & 15);
  const int k0 = ks * 64 + h * 32 + (l >> 4) * 8;
  const int dk = k0 >> 9;
  const int ci = k0 & 511;
  const long sbase = ((long)co * 512 + ci) * 3 + dk;
  ushort4 u0, u1;
  u0.x = f2bf(load_sel(W, sbase + 0 * 3, f));
  u0.y = f2bf(load_sel(W, sbase + 1 * 3, f));
  u0.z = f2bf(load_sel(W, sbase + 2 * 3, f));
  u0.w = f2bf(load_sel(W, sbase + 3 * 3, f));
  u1.x = f2bf(load_sel(W, sbase + 4 * 3, f));
  u1.y = f2bf(load_sel(W, sbase + 5 * 3, f));
  u1.z = f2bf(load_sel(W, sbase + 6 * 3, f));
  u1.w = f2bf(load_sel(W, sbase + 7 * 3, f));
  *(ushort4*)(WF + (long)id * 8) = u0;
  *(ushort4*)(WF + (long)id * 8 + 4) = u1;
}

__device__ void task_wt3v(const void* W, bf16* WT, int f, int Co, int Ci,
                          int id2, int tid) {
  const int i = id2 * 256 + tid;
  const int g4 = Ci >> 2;
  if (i >= Co * g4) return;
  const int co = i / g4, ci = (i - co * g4) * 4;
  const long sbase = ((long)co * Ci + ci) * 3;
  float w[12];
  if (f) {
    const float4* s = (const float4*)((const float*)W + sbase);
    float4 f0 = s[0], f1 = s[1], f2 = s[2];
    w[0]=f0.x; w[1]=f0.y; w[2]=f0.z; w[3]=f0.w; w[4]=f1.x; w[5]=f1.y;
    w[6]=f1.z; w[7]=f1.w; w[8]=f2.x; w[9]=f2.y; w[10]=f2.z; w[11]=f2.w;
  } else {
#pragma unroll
    for (int j = 0; j < 12; ++j) w[j] = load_sel(W, sbase + j, 0);
  }
#pragma unroll
  for (int dk = 0; dk < 3; ++dk) {
    ushort4 u;
    u.x = f2bf(w[0 * 3 + dk]); u.y = f2bf(w[1 * 3 + dk]);
    u.z = f2bf(w[2 * 3 + dk]); u.w = f2bf(w[3 * 3 + dk]);
    *(ushort4*)(WT + ((long)dk * Co + co) * Ci + ci) = u;
  }
}

__device__ void task_cvtv(const void* W, bf16* O, int f, int n, int id2, int tid) {
  const int i = (id2 * 256 + tid) * 4;
  if (i >= n) return;
  ushort4 u;
  if (f) {
    float4 v = *(const float4*)((const float*)W + i);
    u.x = f2bf(v.x); u.y = f2bf(v.y); u.z = f2bf(v.z); u.w = f2bf(v.w);
  } else {
    u.x = f2bf(load_sel(W, i, 0));     u.y = f2bf(load_sel(W, i + 1, 0));
    u.z = f2bf(load_sel(W, i + 2, 0)); u.w = f2bf(load_sel(W, i + 3, 0));
  }
  *(ushort4*)(O + i) = u;
}

__global__ __launch_bounds__(256) void k_prep(
    const void* __restrict__ queries, const void* __restrict__ keys,
    const void* __restrict__ mask,
    const void* __restrict__ kp_w1, const void* __restrict__ kp_b1,
    const void* __restrict__ kp_w2, const void* __restrict__ kp_b2,
    const void* __restrict__ qp_w1, const void* __restrict__ qp_b1,
    const void* __restrict__ qp_w2, const void* __restrict__ qp_b2,
    const void* __restrict__ qp_w3, const void* __restrict__ qp_b3,
    bf16* __restrict__ keysT, bf16* __restrict__ queriesT,
    bf16* __restrict__ w1F, bf16* __restrict__ qw1T,
    bf16* __restrict__ kw2c, bf16* __restrict__ qw2c, bf16* __restrict__ qw3c,
    float* __restrict__ biasf, float* __restrict__ mf, float* __restrict__ kn) {
  __shared__ float smem[32 * 33];
  const int tid = threadIdx.x;
  const int f = detect_f32((const unsigned short*)queries);
  int id = blockIdx.x;

  if (id < 896) { task_cvt_t(keys, keysT, f, CT, T2_, id, 7, smem, tid); return; }
  id -= 896;
  if (id < 600) { task_cvt_t(queries, queriesT, f, CM, T1_, id, 25, smem, tid); return; }
  id -= 600;
  if (id < 768) { task_wfrag(kp_w1, w1F, f, id, tid); return; }
  id -= 768;
  if (id < 13) { task_wt3v(qp_w1, qw1T, f, 160, CM, id, tid); return; }
  id -= 13;
  if (id < 80) { task_cvtv(kp_w2, kw2c, f, 80 * 1024, id, tid); return; }
  id -= 80;
  if (id < 13) { task_cvtv(qp_w2, qw2c, f, 80 * 160, id, tid); return; }
  id -= 13;
  if (id < 7) { task_cvtv(qp_w3, qw3c, f, 80 * 80, id, tid); return; }
  id -= 7;

  if (id == 0) {
    for (int i = tid; i < 1424; i += 256) {
      float v;
      if (i < 1024)      v = load_sel(kp_b1, i, f);
      else if (i < 1104) v = load_sel(kp_b2, i - 1024, f);
      else if (i < 1264) v = load_sel(qp_b1, i - 1104, f);
      else if (i < 1344) v = load_sel(qp_b2, i - 1264, f);
      else               v = load_sel(qp_b3, i - 1344, f);
      biasf[i] = v;
    }
    // zero key-norm accumulator (conv2 atomically accumulates into it)
    for (int i = tid; i < B_ * T2_; i += 256) kn[i] = 0.f;
    return;
  }

  // mask normalize (R2-proven format detection)
  {
    int* s_fmt = (int*)smem;
    const int nmask = B_ * T2_;
    if (tid == 0) s_fmt[0] = 1;
    __syncthreads();
    const unsigned int* wi = (const unsigned int*)mask;
    const int nw = nmask / 4;
    int pri = 0;
    for (int i = tid; i < nw; i += 256) {
      unsigned int w = wi[i];
      if (w == 0u || w == 1u) continue;
      if (w == 0x3F803F80u || w == 0x00003F80u) { pri = max(pri, 2); continue; }
      if (w == 0x3F800000u) continue;
      unsigned int b0 = w & 0xFFu, b1 = (w >> 8) & 0xFFu,
                   b2 = (w >> 16) & 0xFFu, b3 = (w >> 24) & 0xFFu;
      if (b0 <= 1u && b1 <= 1u && b2 <= 1u && b3 <= 1u) pri = max(pri, 3);
      else pri = max(pri, 2);
    }
    if (pri) atomicMax(&s_fmt[0], pri);
    __syncthreads();
    const int fmt = s_fmt[0];
    for (int i = tid; i < nmask; i += 256) {
      int m;
      if (fmt == 3)      m = ((const unsigned char*)mask)[i] != 0;
      else if (fmt == 2) m = ((const unsigned short*)mask)[i] != 0;
      else               m = (wi[i] != 0u);
      mf[i] = (float)m;
    }
  }
}

// ---------------------------------------------------------------------------
// Generic conv tile, BK=32 (R4-proven) + reg-prefetch.
// outmode: 0 = bf16 [n][Cout]; 1 = fp32 [n][Cout];
// 2 = keT [b][80][200] = -2v + atomicAdd v^2 into Y2.
// ---------------------------------------------------------------------------
__device__ void conv_tile(
    const bf16* __restrict__ XT, const bf16* __restrict__ WT,
    const float* __restrict__ bias, void* __restrict__ Y,
    int Cin, int Cout, int T, int KW, int pad, int relu, int outmode,
    int m0, int n0, short* As, short* Bs, float* Y2 = nullptr) {
  const int K = Cin * KW;
  const int tid = threadIdx.x;
  const int wave = tid >> 6;
  const int lane = tid & 63;

  const int row = tid >> 2;
  const int koff = (tid & 3) * 8;
  const int n = n0 + row;
  const int bb = n / T;
  const int t = n - bb * T;

  const int wm = (wave >> 1) * 32;
  const int wn = (wave & 1) * 32;
  const int fm = lane & 15;
  const int quad = lane >> 4;

  f32x4 acc[2][2] = {};

  const short* ap0 = As + (wm + fm) * LDSW + quad * 8;
  const short* bp0 = Bs + (wn + fm) * LDSW + quad * 8;

  auto loadA = [&](int k0) -> uint4 {
    const int k = k0 + koff;
    const int m = m0 + row;
    uint4 v = {0u, 0u, 0u, 0u};
    if (m < Cout && k < K) {
      const int dk = k / Cin;
      const int ci = k - dk * Cin;
      v = *(const uint4*)(WT + ((long)dk * Cout + m) * Cin + ci);
    }
    return v;
  };
  auto loadB = [&](int k0) -> uint4 {
    const int k = k0 + koff;
    uint4 v = {0u, 0u, 0u, 0u};
    if (k < K) {
      const int dk = k / Cin;
      const int ci = k - dk * Cin;
      const int tt = t + dk - pad;
      if (tt >= 0 && tt < T)
        v = *(const uint4*)(XT + ((long)bb * T + tt) * Cin + ci);
    }
    return v;
  };

  uint4 va = loadA(0);
  uint4 vb = loadB(0);

  for (int k0 = 0; k0 < K; k0 += 32) {
    *(uint4*)(As + row * LDSW + koff) = va;
    *(uint4*)(Bs + row * LDSW + koff) = vb;
    if (k0 + 32 < K) {
      va = loadA(k0 + 32);
      vb = loadB(k0 + 32);
    }
    __syncthreads();
    {
      bf16x8 a0 = *(const bf16x8*)(ap0);
      bf16x8 a1 = *(const bf16x8*)(ap0 + 16 * LDSW);
      bf16x8 b0 = *(const bf16x8*)(bp0);
      bf16x8 b1 = *(const bf16x8*)(bp0 + 16 * LDSW);
      acc[0][0] = __builtin_amdgcn_mfma_f32_16x16x32_bf16(a0, b0, acc[0][0], 0, 0, 0);
      acc[0][1] = __builtin_amdgcn_mfma_f32_16x16x32_bf16(a0, b1, acc[0][1], 0, 0, 0);
      acc[1][0] = __builtin_amdgcn_mfma_f32_16x16x32_bf16(a1, b0, acc[1][0], 0, 0, 0);
      acc[1][1] = __builtin_amdgcn_mfma_f32_16x16x32_bf16(a1, b1, acc[1][1], 0, 0, 0);
    }
    __syncthreads();
  }

#pragma unroll
  for (int mi = 0; mi < 2; ++mi) {
    const int mrow = m0 + wm + mi * 16 + quad * 4;
    if (mrow >= Cout) continue;
    float bi[4];
#pragma unroll
    for (int r = 0; r < 4; ++r) bi[r] = bias[mrow + r];
#pragma unroll
    for (int ni = 0; ni < 2; ++ni) {
      const int ncol = n0 + wn + ni * 16 + fm;
      float o[4];
#pragma unroll
      for (int r = 0; r < 4; ++r) {
        float v = acc[mi][ni][r] + bi[r];
        if (relu) v = fmaxf(v, 0.f);
        o[r] = v;
      }
      if (outmode == 0) {
        ushort4 u;
        u.x = f2bf(o[0]); u.y = f2bf(o[1]); u.z = f2bf(o[2]); u.w = f2bf(o[3]);
        *(ushort4*)((bf16*)Y + (long)ncol * Cout + mrow) = u;
      } else if (outmode == 1) {
        *(float4*)((float*)Y + (long)ncol * Cout + mrow) =
            make_float4(o[0], o[1], o[2], o[3]);
      } else {
        // keT [b][Cout][T] = -2v, channel-major for coalesced dist reads
        const int bb2 = ncol / T;
        const int tloc = ncol - bb2 * T;
        float s4 = 0.f;
#pragma unroll
        for (int r = 0; r < 4; ++r) {
          ((float*)Y)[((long)bb2 * Cout + mrow + r) * T + tloc] = -2.f * o[r];
          s4 = fmaf(o[r], o[r], s4);
        }
        atomicAdd(&Y2[ncol], s4);
      }
    }
  }
}

// ---------------------------------------------------------------------------
// Key-conv1, 128x64 tile, BK=128 (NEW): 12 barrier-pairs instead of 24,
// 32 MFMAs per pair. A direct from w1F with 64-k-granular ping-pong:
// nxt(ks0+1) loads before the barrier (hides under stage+drain); cur(ks0+2)
// reloads between the two MFMA half-blocks (hides under 16 MFMAs).
// Accumulation order (ks ascending) identical to R7 -> bit-identical output.
// ---------------------------------------------------------------------------
__device__ void conv_key128(
    const bf16* __restrict__ XT, const bf16* __restrict__ WF,
    const float* __restrict__ bias, bf16* __restrict__ Y,
    int panel, int n0, short* Bs) {
  const int Cin = CT, Cout = 1024, T = T2_;
  const int tid = threadIdx.x;
  const int wave = tid >> 6;
  const int lane = tid & 63;
  const int m0 = panel * 128;

  // B staging: rowb = tid>>2 (0..63); 64 B per thread (4 x uint4)
  const int rowb = tid >> 2;
  const int nb = n0 + rowb;
  const int bbb = nb / T;
  const int tb = nb - bbb * T;
  const int kcb = (tid & 3) * 32;

  const int w2 = wave >> 1;
  const int wn = (wave & 1) * 32;
  const int fm = lane & 15;
  const int quad = lane >> 4;

  f32x4 acc[4][2] = {};
  const short* bp0 = Bs + (wn + fm) * LDSW2B + quad * 8;

  uint4 vb[4];
  auto loadB = [&](int k0) {
    const int dk = k0 >> 9;           // 512 % 128 == 0: no dk straddle
    const int ci0 = k0 & 511;
    const int tt = tb + dk - 1;
    if (tt >= 0 && tt < T) {
      const bf16* src = XT + ((long)bbb * T + tt) * Cin + ci0 + kcb;
#pragma unroll
      for (int r = 0; r < 4; ++r) vb[r] = *(const uint4*)(src + r * 8);
    } else {
      uint4 z = {0u, 0u, 0u, 0u};
#pragma unroll
      for (int r = 0; r < 4; ++r) vb[r] = z;
    }
  };

  bf16x8 a0c[4], a1c[4], a0n[4], a1n[4];
  auto loadA = [&](int ks, bf16x8 d0[4], bf16x8 d1[4]) {
    const long abase = ((((long)panel * 24 + ks) * 2 + w2) * 4096) + lane * 8;
#pragma unroll
    for (int mi = 0; mi < 4; ++mi) {
      d0[mi] = *(const bf16x8*)(WF + abase + (mi * 2 + 0) * 512);
      d1[mi] = *(const bf16x8*)(WF + abase + (mi * 2 + 1) * 512);
    }
  };

  loadB(0);
  loadA(0, a0c, a1c);

  for (int K0 = 0; K0 < 1536; K0 += 128) {
    const int ks0 = K0 >> 6;
    {
      short* dstb = Bs + rowb * LDSW2B + kcb;
#pragma unroll
      for (int r = 0; r < 4; ++r) *(uint4*)(dstb + r * 8) = vb[r];
    }
    const bool more = (K0 + 128 < 1536);
    if (more) loadB(K0 + 128);
    loadA(ks0 + 1, a0n, a1n);          // second 64-k half of this step
    __syncthreads();
    // ---- slices 0,1: cur = ks0 (k cols 0..63) ----
    {
      bf16x8 b00 = *(const bf16x8*)(bp0);
      bf16x8 b01 = *(const bf16x8*)(bp0 + 16 * LDSW2B);
#pragma unroll
      for (int mi = 0; mi < 4; ++mi) {
        acc[mi][0] = __builtin_amdgcn_mfma_f32_16x16x32_bf16(a0c[mi], b00, acc[mi][0], 0, 0, 0);
        acc[mi][1] = __builtin_amdgcn_mfma_f32_16x16x32_bf16(a0c[mi], b01, acc[mi][1], 0, 0, 0);
      }
      bf16x8 b10 = *(const bf16x8*)(bp0 + 32);
      bf16x8 b11 = *(const bf16x8*)(bp0 + 16 * LDSW2B + 32);
#pragma unroll
      for (int mi = 0; mi < 4; ++mi) {
        acc[mi][0] = __builtin_amdgcn_mfma_f32_16x16x32_bf16(a1c[mi], b10, acc[mi][0], 0, 0, 0);
        acc[mi][1] = __builtin_amdgcn_mfma_f32_16x16x32_bf16(a1c[mi], b11, acc[mi][1], 0, 0, 0);
      }
    }
    if (more) loadA(ks0 + 2, a0c, a1c);  // first half of NEXT step; hides
                                         // under the 16 MFMAs below
    // ---- slices 2,3: nxt = ks0+1 (k cols 64..127) ----
    {
      bf16x8 b20 = *(const bf16x8*)(bp0 + 64);
      bf16x8 b21 = *(const bf16x8*)(bp0 + 16 * LDSW2B + 64);
#pragma unroll
      for (int mi = 0; mi < 4; ++mi) {
        acc[mi][0] = __builtin_amdgcn_mfma_f32_16x16x32_bf16(a0n[mi], b20, acc[mi][0], 0, 0, 0);
        acc[mi][1] = __builtin_amdgcn_mfma_f32_16x16x32_bf16(a0n[mi], b21, acc[mi][1], 0, 0, 0);
      }
      bf16x8 b30 = *(const bf16x8*)(bp0 + 96);
      bf16x8 b31 = *(const bf16x8*)(bp0 + 16 * LDSW2B + 96);
#pragma unroll
      for (int mi = 0; mi < 4; ++mi) {
        acc[mi][0] = __builtin_amdgcn_mfma_f32_16x16x32_bf16(a1n[mi], b30, acc[mi][0], 0, 0, 0);
        acc[mi][1] = __builtin_amdgcn_mfma_f32_16x16x32_bf16(a1n[mi], b31, acc[mi][1], 0, 0, 0);
      }
    }
    __syncthreads();
  }

#pragma unroll
  for (int mi = 0; mi < 4; ++mi) {
    const int mrow = m0 + w2 * 64 + mi * 16 + quad * 4;
    float bi[4];
#pragma unroll
    for (int r = 0; r < 4; ++r) bi[r] = bias[mrow + r];
#pragma unroll
    for (int ni = 0; ni < 2; ++ni) {
      const int ncol = n0 + wn + ni * 16 + fm;
      const long base = (long)ncol * Cout + mrow;
      ushort4 u;
      u.x = f2bf(fmaxf(acc[mi][ni][0] + bi[0], 0.f));
      u.y = f2bf(fmaxf(acc[mi][ni][1] + bi[1], 0.f));
      u.z = f2bf(fmaxf(acc[mi][ni][2] + bi[2], 0.f));
      u.w = f2bf(fmaxf(acc[mi][ni][3] + bi[3], 0.f));
      *(ushort4*)(Y + base) = u;
    }
  }
}

__global__ __launch_bounds__(256) void k_conv1(
    const bf16* __restrict__ keysT, const bf16* __restrict__ w1F,
    const float* __restrict__ b_k1, bf16* __restrict__ ke1T,
    const bf16* __restrict__ queriesT, const bf16* __restrict__ qw1T,
    const float* __restrict__ b_q1, bf16* __restrict__ qe1T) {
  // 17.4 KB: key path needs 64*LDSW2B shorts; query path needs 2*64*LDSW (fits)
  __shared__ __align__(16) short smem[64 * LDSW2B];
  int j = blockIdx.x;
  if (j < 200) {
    // panel = j&7 -> XCD-affine: each XCD keeps its 384 KB A-panel L2-resident.
    conv_key128(keysT, w1F, b_k1, ke1T, j & 7, (j >> 3) * 64, smem);
  } else {
    j -= 200;
    conv_tile(queriesT, qw1T, b_q1, qe1T, CM, 160, T1_, 3, 1, 1, 0,
              (j / 100) * 64, (j % 100) * 64, smem, smem + 64 * LDSW);
  }
}

// ---------------------------------------------------------------------------
// Fused query conv2+conv3 (R4-proven) + qn (||q||^2) epilogue.
// ---------------------------------------------------------------------------
__device__ void conv23_tile(
    const bf16* __restrict__ qe1T, const bf16* __restrict__ qw2c,
    const float* __restrict__ b_q2, const bf16* __restrict__ qw3c,
    const float* __restrict__ b_q3, float* __restrict__ qeT,
    float* __restrict__ qn, int n0, short* smem) {
  short* sIn = smem;
  short* sW2 = smem + 64 * LDSW3;
  short* sC  = smem;
  short* sW3 = smem + 64 * LDSW3;
  const int tid = threadIdx.x;
  const int wave = tid >> 6;
  const int lane = tid & 63;
  const int fm = lane & 15;
  const int quad = lane >> 4;

#pragma unroll
  for (int c = tid; c < 1280; c += 256) {
    const int row = c / 20, kc = (c - row * 20) * 8;
    uint4 v = *(const uint4*)(qe1T + (long)(n0 + row) * 160 + kc);
    *(uint4*)(sIn + row * LDSW3 + kc) = v;
  }
  for (int c = tid; c < 1600; c += 256) {
    const int row = c / 20, kc = (c - row * 20) * 8;
    uint4 v = *(const uint4*)(qw2c + (long)row * 160 + kc);
    *(uint4*)(sW2 + row * LDSW3 + kc) = v;
  }
  __syncthreads();

  f32x4 acc1[5] = {};
#pragma unroll
  for (int ks = 0; ks < 5; ++ks) {
    bf16x8 b = *(const bf16x8*)(sIn + (16 * wave + fm) * LDSW3 + ks * 32 + quad * 8);
#pragma unroll
    for (int mt = 0; mt < 5; ++mt) {
      bf16x8 a = *(const bf16x8*)(sW2 + (16 * mt + fm) * LDSW3 + ks * 32 + quad * 8);
      acc1[mt] = __builtin_amdgcn_mfma_f32_16x16x32_bf16(a, b, acc1[mt], 0, 0, 0);
    }
  }
  __syncthreads();

#pragma unroll
  for (int mt = 0; mt < 5; ++mt) {
    const int ch = 16 * mt + quad * 4;
    const float4 b2 = *(const float4*)(b_q2 + ch);
    ushort4 u;
    u.x = f2bf(fmaxf(acc1[mt][0] + b2.x, 0.f));
    u.y = f2bf(fmaxf(acc1[mt][1] + b2.y, 0.f));
    u.z = f2bf(fmaxf(acc1[mt][2] + b2.z, 0.f));
    u.w = f2bf(fmaxf(acc1[mt][3] + b2.w, 0.f));
    *(ushort4*)(sC + (16 * wave + fm) * LDSW4 + ch) = u;
  }
  if (tid < 128) {
    const int row = tid >> 1, off = 80 + (tid & 1) * 8;
    uint4 z = {0u, 0u, 0u, 0u};
    *(uint4*)(sC + row * LDSW4 + off) = z;
  }
  for (int c = tid; c < 800; c += 256) {
    const int row = c / 10, kc = (c - row * 10) * 8;
    uint4 v = *(const uint4*)(qw3c + (long)row * 80 + kc);
    *(uint4*)(sW3 + row * LDSW4 + kc) = v;
  }
  if (tid < 160) {
    const int row = tid >> 1, off = 80 + (tid & 1) * 8;
    uint4 z = {0u, 0u, 0u, 0u};
    *(uint4*)(sW3 + row * LDSW4 + off) = z;
  }
  __syncthreads();

  f32x4 acc2[5] = {};
#pragma unroll
  for (int ks = 0; ks < 3; ++ks) {
    bf16x8 b = *(const bf16x8*)(sC + (16 * wave + fm) * LDSW4 + ks * 32 + quad * 8);
#pragma unroll
    for (int mt = 0; mt < 5; ++mt) {
      bf16x8 a = *(const bf16x8*)(sW3 + (16 * mt + fm) * LDSW4 + ks * 32 + quad * 8);
      acc2[mt] = __builtin_amdgcn_mfma_f32_16x16x32_bf16(a, b, acc2[mt], 0, 0, 0);
    }
  }

  const int pos = n0 + 16 * wave + fm;
  float p = 0.f;
#pragma unroll
  for (int mt = 0; mt < 5; ++mt) {
    const int ch = 16 * mt + quad * 4;
    const float4 b3 = *(const float4*)(b_q3 + ch);
    float4 o = make_float4(acc2[mt][0] + b3.x, acc2[mt][1] + b3.y,
                           acc2[mt][2] + b3.z, acc2[mt][3] + b3.w);
    p = fmaf(o.x, o.x, p); p = fmaf(o.y, o.y, p);
    p = fmaf(o.z, o.z, p); p = fmaf(o.w, o.w, p);
    *(float4*)(qeT + (long)pos * CA + ch) = o;
  }
  p += __shfl_xor(p, 16, 64);
  p += __shfl_xor(p, 32, 64);
  if (quad == 0) qn[pos] = p;
}

__global__ __launch_bounds__(256) void k_conv2f(
    const bf16* __restrict__ ke1T, const bf16* __restrict__ kw2c,
    const float* __restrict__ b_k2, float* __restrict__ keT,
    float* __restrict__ kn,
    const bf16* __restrict__ qe1T, const bf16* __restrict__ qw2c,
    const float* __restrict__ b_q2, const bf16* __restrict__ qw3c,
    const float* __restrict__ b_q3, float* __restrict__ qeT,
    float* __restrict__ qn) {
  __shared__ __align__(16) short smem[64 * LDSW3 + 80 * LDSW3];
  int j = blockIdx.x;
  if (j < 50) {
    conv_tile(ke1T, kw2c, b_k2, keT, 1024, CA, T2_, 1, 0, 0, 2,
              (j / 25) * 64, (j % 25) * 64, smem, smem + 64 * LDSW, kn);
  } else {
    conv23_tile(qe1T, qw2c, b_q2, qw3c, b_q3, qeT, qn, (j - 50) * 64, smem);
  }
}

// ---------------------------------------------------------------------------
// dist: 4 t1-rows per block, 2-phase reduction (R7-proven).
// ---------------------------------------------------------------------------
__global__ __launch_bounds__(256) void k_dist(
    const float* __restrict__ qeT, const float* __restrict__ keT2,
    const float* __restrict__ kn, const float* __restrict__ qn,
    const void* __restrict__ prior, const float* __restrict__ mf,
    void* __restrict__ out, const unsigned short* __restrict__ qprobe) {
  __shared__ float sq[4 * CA];
  __shared__ float sqn[4];
  __shared__ float redA[16], redB[16], redC[16], redD[16];
  const int f = detect_f32(qprobe);
  const int b = blockIdx.y;
  const int t1base = blockIdx.x * 4;
  const int tid = threadIdx.x;
  const int wid = tid >> 6;

  const int t2 = tid;
  const bool valid = (t2 < T2_);
  const long N = (long)B_ * T1_ * T2_;

  float pr[4] = {0.f, 0.f, 0.f, 0.f};
  float mval = 1.f;
  if (valid) {
#pragma unroll
    for (int u = 0; u < 4; ++u)
      pr[u] = load_sel(prior, ((long)b * T1_ + t1base + u) * T2_ + t2, f);
    mval = mf[b * T2_ + t2];
  }

  for (int i = tid; i < 4 * CA; i += 256) {
    int u = i / CA, c = i - u * CA;
    sq[i] = qeT[((long)b * T1_ + t1base + u) * CA + c];
  }
  if (tid < 4) sqn[tid] = qn[b * T1_ + t1base + tid];
  __syncthreads();

  float x[4] = {-INFINITY, -INFINITY, -INFINITY, -INFINITY};
  if (valid) {
    const float* kp = keT2 + (long)b * CA * T2_ + t2;
    const float knv = kn[b * T2_ + t2];
    float a0 = 0.f, a1 = 0.f, a2 = 0.f, a3 = 0.f;
#pragma unroll 2
    for (int j = 0; j < CA; j += 4) {
      const float4 q0 = *(const float4*)(sq + 0 * CA + j);
      const float4 q1 = *(const float4*)(sq + 1 * CA + j);
      const float4 q2 = *(const float4*)(sq + 2 * CA + j);
      const float4 q3 = *(const float4*)(sq + 3 * CA + j);
      const float k0v = kp[(j + 0) * T2_];
      const float k1v = kp[(j + 1) * T2_];
      const float k2v = kp[(j + 2) * T2_];
      const float k3v = kp[(j + 3) * T2_];
      a0 = fmaf(k0v, q0.x, a0); a0 = fmaf(k1v, q0.y, a0);
      a0 = fmaf(k2v, q0.z, a0); a0 = fmaf(k3v, q0.w, a0);
      a1 = fmaf(k0v, q1.x, a1); a1 = fmaf(k1v, q1.y, a1);
      a1 = fmaf(k2v, q1.z, a1); a1 = fmaf(k3v, q1.w, a1);
      a2 = fmaf(k0v, q2.x, a2); a2 = fmaf(k1v, q2.y, a2);
      a2 = fmaf(k2v, q2.z, a2); a2 = fmaf(k3v, q2.w, a2);
      a3 = fmaf(k0v, q3.x, a3); a3 = fmaf(k1v, q3.y, a3);
      a3 = fmaf(k2v, q3.z, a3); a3 = fmaf(k3v, q3.w, a3);
    }
    x[0] = -0.0005f * (a0 + sqn[0] + knv);
    x[1] = -0.0005f * (a1 + sqn[1] + knv);
    x[2] = -0.0005f * (a2 + sqn[2] + knv);
    x[3] = -0.0005f * (a3 + sqn[3] + knv);
  }

  float y[4], ym[4];
#pragma unroll
  for (int u = 0; u < 4; ++u) {
    if (valid) {
      const float lpr = __logf(fmaxf(pr[u], 0.f) + 1e-8f);
      y[u] = x[u] + lpr;
    } else {
      y[u] = -INFINITY;
    }
    ym[u] = (valid && mval == 0.f) ? y[u] : -INFINITY;
  }

  // --- phase A: max(x) and maskedmax(y) ---
  float m1[4], m2[4];
#pragma unroll
  for (int u = 0; u < 4; ++u) { m1[u] = x[u]; m2[u] = ym[u]; }
#pragma unroll
  for (int o = 32; o > 0; o >>= 1)
#pragma unroll
    for (int u = 0; u < 4; ++u) {
      m1[u] = fmaxf(m1[u], __shfl_down(m1[u], o, 64));
      m2[u] = fmaxf(m2[u], __shfl_down(m2[u], o, 64));
    }
  if ((tid & 63) == 0)
#pragma unroll
    for (int u = 0; u < 4; ++u) {
      redA[wid * 4 + u] = m1[u];
      redB[wid * 4 + u] = m2[u];
    }
  __syncthreads();
  float M1[4], M2[4];
#pragma unroll
  for (int u = 0; u < 4; ++u) {
    M1[u] = fmaxf(fmaxf(redA[u], redA[4 + u]), fmaxf(redA[8 + u], redA[12 + u]));
    M2[u] = fmaxf(fmaxf(redB[u], redB[4 + u]), fmaxf(redB[8 + u], redB[12 + u]));
  }

  // --- phase B: both exp-sums ---
  float e2[4], s1[4], s2[4];
#pragma unroll
  for (int u = 0; u < 4; ++u) {
    s1[u] = (x[u] == -INFINITY) ? 0.f : __expf(x[u] - M1[u]);
    e2[u] = (ym[u] == -INFINITY) ? 0.f : __expf(ym[u] - M2[u]);
    s2[u] = e2[u];
  }
#pragma unroll
  for (int o = 32; o > 0; o >>= 1)
#pragma unroll
    for (int u = 0; u < 4; ++u) {
      s1[u] += __shfl_down(s1[u], o, 64);
      s2[u] += __shfl_down(s2[u], o, 64);
    }
  if ((tid & 63) == 0)
#pragma unroll
    for (int u = 0; u < 4; ++u) {
      redC[wid * 4 + u] = s1[u];
      redD[wid * 4 + u] = s2[u];
    }
  __syncthreads();

#pragma unroll
  for (int u = 0; u < 4; ++u) {
    const float S1 = redC[u] + redC[4 + u] + redC[8 + u] + redC[12 + u];
    const float S2 = redD[u] + redD[4 + u] + redD[8 + u] + redD[12 + u];
    if (valid) {
      const float logZ = __logf(S1);
      const float lp = y[u] - M1[u] - logZ;
      const float a = (S2 > 0.f) ? (e2[u] / S2) : 0.f;
      const long oidx = ((long)b * T1_ + t1base + u) * T2_ + t2;
      if (f) {
        ((float*)out)[N + oidx] = lp;
        ((float*)out)[oidx] = a;
      } else {
        ((bf16*)out)[N + oidx] = __float2bfloat16(lp);
        ((bf16*)out)[oidx] = __float2bfloat16(a);
      }
    }
  }
}

// ---------------------------------------------------------------------------
extern "C" void kernel_launch(void* const* d_in, const int* in_sizes, int n_in,
                              void* d_out, int out_size, void* d_ws, size_t ws_size,
                              hipStream_t stream) {
  const void* queries = d_in[0];
  const void* keys    = d_in[1];
  const void* mask    = d_in[3];
  const void* prior   = d_in[4];
  const void* kp_w1 = d_in[5];
  const void* kp_b1 = d_in[6];
  const void* kp_w2 = d_in[7];
  const void* kp_b2 = d_in[8];
  const void* qp_w1 = d_in[9];
  const void* qp_b1 = d_in[10];
  const void* qp_w2 = d_in[11];
  const void* qp_b2 = d_in[12];
  const void* qp_w3 = d_in[13];
  const void* qp_b3 = d_in[14];

  // ---- Workspace (R4 layout) ----
  float* keT   = (float*)d_ws;            // 128,000 f  [b][80][200] = -2k
  float* qeT   = keT + 128000;            // 512,000 f  [b][800][80]
  float* mf    = qeT + 512000;            //   1,600 f
  float* biasf = mf + 1600;               //   1,440 f
  float* kn    = biasf + 1440;            //   1,600 f  ||k||^2
  float* qn    = kn + 1600;               //   6,400 f  ||q||^2
  bf16* keysT    = (bf16*)(qn + 6400);    //   819,200
  bf16* queriesT = keysT + 819200;        //   512,000
  bf16* w1F      = queriesT + 512000;     // 1,572,864 (fragment-ordered)
  bf16* qw1T     = w1F + 1572864;         //    38,400
  bf16* kw2c     = qw1T + 38400;          //    81,920
  bf16* qw2c     = kw2c + 81920;          //    12,800
  bf16* qw3c     = qw2c + 12800;          //     6,400
  bf16* ke1T     = qw3c + 6400;           // 1,638,400
  bf16* qe1T     = ke1T + 1638400;        // 1,024,000

  float* b_k1 = biasf;          // 1024
  float* b_k2 = biasf + 1024;   // 80
  float* b_q1 = biasf + 1104;   // 160
  float* b_q2 = biasf + 1264;   // 80
  float* b_q3 = biasf + 1344;   // 80

  // 1) fused prep (also zeroes kn); 2379 = 896+600+768+13+80+13+7+2
  k_prep<<<2379, 256, 0, stream>>>(
      queries, keys, mask,
      kp_w1, kp_b1, kp_w2, kp_b2,
      qp_w1, qp_b1, qp_w2, qp_b2, qp_w3, qp_b3,
      keysT, queriesT, w1F, qw1T, kw2c, qw2c, qw3c, biasf, mf, kn);

  // 2) conv1: key 128x64 BK=128 (200) + query 64x64 (300)
  k_conv1<<<500, 256, 0, stream>>>(keysT, w1F, b_k1, ke1T,
                                   queriesT, qw1T, b_q1, qe1T);

  // 3) key conv2 -> -2k + kn (50) + fused query conv2+3 -> qeT + qn (100)
  k_conv2f<<<150, 256, 0, stream>>>(ke1T, kw2c, b_k2, keT, kn,
                                    qe1T, qw2c, b_q2, qw3c, b_q3, qeT, qn);

  // 4) dist (2-phase reduction)
  k_dist<<<dim3(200, B_), 256, 0, stream>>>(
      qeT, keT, kn, qn, prior, mf, d_out, (const unsigned short*)queries);
}